// Round 6
// baseline (2600.669 us; speedup 1.0000x reference)
//
#include <hip/hip_runtime.h>

typedef __bf16 bf16x8 __attribute__((ext_vector_type(8)));
typedef float f32x4 __attribute__((ext_vector_type(4)));
typedef unsigned short u16;
typedef unsigned int u32;

// ---------------- helpers ----------------
__device__ __forceinline__ u16 f2b(float f) {
    union { float f; u32 u; } v; v.f = f;
    u32 r = v.u + 0x7fffu + ((v.u >> 16) & 1u);
    return (u16)(r >> 16);
}
__device__ __forceinline__ float b2f(u16 u) {
    union { u32 u; float f; } v; v.u = ((u32)u) << 16; return v.f;
}
__device__ __forceinline__ void gl_lds16(const u16* g, u16* l) {
    __builtin_amdgcn_global_load_lds(
        (const __attribute__((address_space(1))) void*)g,
        (__attribute__((address_space(3))) void*)l, 16, 0, 0);
}

// ---------------- LN (+shift+window-partition) ----------------
__global__ __launch_bounds__(256) void ln_kernel(
    const float* __restrict__ h, u16* __restrict__ out,
    const float* __restrict__ g, const float* __restrict__ bb,
    int D, int dsh, int shifted, int mode)
{
    const int lane = threadIdx.x & 63;
    const int t = blockIdx.x * 4 + (threadIdx.x >> 6);
    const float4 xv = *(const float4*)(h + (size_t)t * 256 + lane * 4);
    float s = xv.x + xv.y + xv.z + xv.w;
    float s2 = xv.x*xv.x + xv.y*xv.y + xv.z*xv.z + xv.w*xv.w;
    #pragma unroll
    for (int o = 32; o > 0; o >>= 1) { s += __shfl_xor(s, o); s2 += __shfl_xor(s2, o); }
    const float mu = s * 0.00390625f;
    const float var = s2 * 0.00390625f - mu * mu;
    const float rs = 1.0f / sqrtf(var + 1e-5f);
    const int c0 = lane * 4;
    const float4 gv = *(const float4*)(g + c0);
    const float4 bv = *(const float4*)(bb + c0);
    ushort4 o4;
    o4.x = f2b((xv.x - mu) * rs * gv.x + bv.x);
    o4.y = f2b((xv.y - mu) * rs * gv.y + bv.y);
    o4.z = f2b((xv.z - mu) * rs * gv.z + bv.z);
    o4.w = f2b((xv.w - mu) * rs * gv.w + bv.w);
    size_t oidx;
    if (mode == 1) {
        oidx = (size_t)t * 256 + c0;
    } else {
        const int b = t >> (dsh + 12);
        const int rem = t & ((1 << (dsh + 12)) - 1);
        int d = rem >> 12;
        const int l = rem & 4095;
        int hh = l >> 6, ww = l & 63;
        if (shifted) { d = d ? d - 1 : D - 1; hh = (hh - 4) & 63; ww = (ww - 4) & 63; }
        const int widx = (b << (dsh + 5)) + ((d >> 1) << 6) + ((hh >> 3) << 3) + (ww >> 3);
        const int n = ((d & 1) << 6) + ((hh & 7) << 3) + (ww & 7);
        oidx = ((size_t)(widx * 128 + n)) * 256 + c0;
    }
    *(ushort4*)(out + oidx) = o4;
}

// ---------------- fp32 -> bf16 cast ----------------
__global__ __launch_bounds__(256) void cast_kernel(const float* __restrict__ in, u16* __restrict__ out, int n4)
{
    const int i = blockIdx.x * 256 + threadIdx.x;
    if (i >= n4) return;
    const float4 v = ((const float4*)in)[i];
    ushort4 o; o.x = f2b(v.x); o.y = f2b(v.y); o.z = f2b(v.z); o.w = f2b(v.w);
    ((ushort4*)out)[i] = o;
}

// ---------------- weight transpose+cast ----------------
__global__ __launch_bounds__(256) void wt_kernel(const float* __restrict__ src, u16* __restrict__ dst, int K, int N)
{
    const size_t base = (size_t)blockIdx.y * K * N;
    const int idx = blockIdx.x * 256 + threadIdx.x;
    const int k = idx / N, n = idx - k * N;
    dst[base + (size_t)n * K + k] = f2b(src[base + idx]);
}

// ---------------- W1 fragment-major pack ----------------
// dst[((c*8+kt)*4+n)*512 + lane*8 + e] = W1[kt*32 + (lane>>4)*8 + e][c*64 + n*16 + (lane&15)]
__global__ __launch_bounds__(256) void wt1f_kernel(const float* __restrict__ src, u16* __restrict__ dst)
{
    const size_t base = (size_t)blockIdx.y * 262144;
    const int t = blockIdx.x * 256 + threadIdx.x;   // 0..262143
    const int e = t & 7, lane = (t >> 3) & 63, n = (t >> 9) & 3, kt = (t >> 11) & 7, c = t >> 14;
    const int k = kt * 32 + (lane >> 4) * 8 + e;
    const int mid = c * 64 + n * 16 + (lane & 15);
    dst[base + t] = f2b(src[base + (size_t)k * 1024 + mid]);
}

// ---------------- W2 fragment-major pack (with K-permutation m()) ----------------
// dst[((c*2+kt)*16+nt)*512 + lane*8 + e] = W2[c*64 + m(kt,quad,e)][nt*16 + (lane&15)]
__global__ __launch_bounds__(256) void wt2f_kernel(const float* __restrict__ src, u16* __restrict__ dst)
{
    const size_t base = (size_t)blockIdx.y * 262144;
    const int t = blockIdx.x * 256 + threadIdx.x;
    const int e = t & 7, lane = (t >> 3) & 63, nt = (t >> 9) & 15, kt = (t >> 13) & 1, c = t >> 14;
    const int q = lane >> 4;
    const int mid = (2 * kt + (e >> 2)) * 16 + q * 4 + (e & 3);
    const int k = c * 64 + mid;
    const int out = nt * 16 + (lane & 15);
    dst[base + t] = f2b(src[base + (size_t)k * 256 + out]);
}

// ---------------- MFMA bf16 GEMM, 128x128 tile ----------------
struct GemmP {
    const u16* A; const u16* Bt;
    int K;
    const float* bias;
    u16* outb;
    float* outf;
    const float* hin; float* hout;
    int D, shifted, nwsh, row_off;
};

template <int EPI>
__global__ __launch_bounds__(256, 2) void gemm_kernel(GemmP p)
{
    __shared__ __align__(16) char smem[33792];  // 2x(As 8K | Bs 8K); CF 64x132 f32 overlay
    float* CF = (float*)smem;

    const int tid = threadIdx.x;
    const int m0 = blockIdx.x * 128, n0 = blockIdx.y * 128;
    const int K = p.K;
    const int lane = tid & 63;
    const int wv = tid >> 6;
    const int wm = (wv & 1) * 64, wn = (wv >> 1) * 64;
    const int l16 = lane & 15, quad = lane >> 4;

    f32x4 acc[4][4];
    #pragma unroll
    for (int a = 0; a < 4; a++)
        #pragma unroll
        for (int b = 0; b < 4; b++)
            acc[a][b] = f32x4{0.f, 0.f, 0.f, 0.f};

    const int lrow = lane >> 2;
    const int c16s = (lane & 3) ^ (lrow & 3);
    const int rA0 = wv * 16;
    const u16* Ag = p.A + (size_t)(m0 + rA0 + lrow) * K + c16s * 8;
    const u16* Bg = p.Bt + (size_t)(n0 + rA0 + lrow) * K + c16s * 8;
    const size_t j64 = (size_t)64 * K;
    const int fslot = (quad ^ (l16 & 3)) * 8;

    {
        u16* Al = (u16*)smem + rA0 * 32;
        u16* Bl = (u16*)(smem + 8192) + rA0 * 32;
        gl_lds16(Ag, Al);
        gl_lds16(Ag + j64, Al + 64 * 32);
        gl_lds16(Bg, Bl);
        gl_lds16(Bg + j64, Bl + 64 * 32);
    }
    __syncthreads();

    int kb = 0;
    for (int k0 = 0; k0 < K; k0 += 32, kb ^= 1) {
        if (k0 + 32 < K) {
            char* nb = smem + (kb ^ 1) * 16384;
            u16* Al = (u16*)nb + rA0 * 32;
            u16* Bl = (u16*)(nb + 8192) + rA0 * 32;
            gl_lds16(Ag + k0 + 32, Al);
            gl_lds16(Ag + j64 + k0 + 32, Al + 64 * 32);
            gl_lds16(Bg + k0 + 32, Bl);
            gl_lds16(Bg + j64 + k0 + 32, Bl + 64 * 32);
        }
        const u16* As = (const u16*)(smem + kb * 16384);
        const u16* Bs = (const u16*)(smem + kb * 16384 + 8192);
        bf16x8 af[4], bfr[4];
        #pragma unroll
        for (int mt = 0; mt < 4; mt++) af[mt] = *(const bf16x8*)(As + (wm + mt * 16 + l16) * 32 + fslot);
        #pragma unroll
        for (int nt = 0; nt < 4; nt++) bfr[nt] = *(const bf16x8*)(Bs + (wn + nt * 16 + l16) * 32 + fslot);
        #pragma unroll
        for (int mt = 0; mt < 4; mt++)
            #pragma unroll
            for (int nt = 0; nt < 4; nt++)
                acc[mt][nt] = __builtin_amdgcn_mfma_f32_16x16x32_bf16(af[mt], bfr[nt], acc[mt][nt], 0, 0, 0);
        __syncthreads();
    }

    const int crow = tid >> 2;
    const int p4 = (tid & 3) * 4;
    #pragma unroll
    for (int c = 0; c < 2; c++) {
        if (c) __syncthreads();
        if ((wv & 1) == c) {
            #pragma unroll
            for (int mt = 0; mt < 4; mt++)
                #pragma unroll
                for (int nt = 0; nt < 4; nt++)
                    #pragma unroll
                    for (int i = 0; i < 4; i++)
                        CF[(mt * 16 + quad * 4 + i) * 132 + wn + nt * 16 + l16] = acc[mt][nt][i];
        }
        __syncthreads();
        const int rowg = m0 + c * 64 + crow;
        size_t tokbase = 0;
        if constexpr (EPI == 1) {
            const int widx = rowg >> 7, n = rowg & 127;
            const int b = widx >> p.nwsh, rem = widx & ((1 << p.nwsh) - 1);
            int dd = ((rem >> 6) << 1) + (n >> 6);
            int hh = (((rem >> 3) & 7) << 3) + ((n >> 3) & 7);
            int ww = ((rem & 7) << 3) + (n & 7);
            if (p.shifted) { dd = (dd + 1 == p.D) ? 0 : dd + 1; hh = (hh + 4) & 63; ww = (ww + 4) & 63; }
            tokbase = ((size_t)((b * p.D + dd) * 4096 + hh * 64 + ww)) * 256;
        } else if constexpr (EPI == 3) {
            tokbase = (size_t)(p.row_off + rowg) * 256;
        }
        #pragma unroll
        for (int j = 0; j < 8; j++) {
            const int colf = j * 16 + p4;
            const int colg = n0 + colf;
            const float4 t = *(const float4*)(CF + crow * 132 + colf);
            const float4 bi = (EPI <= 3) ? *(const float4*)(p.bias + colg) : float4{0.f,0.f,0.f,0.f};
            if constexpr (EPI == 0) {
                const float sc = (colg < 256) ? 0.125f : 1.0f;
                ushort4 pk;
                pk.x = f2b((t.x + bi.x) * sc);
                pk.y = f2b((t.y + bi.y) * sc);
                pk.z = f2b((t.z + bi.z) * sc);
                pk.w = f2b((t.w + bi.w) * sc);
                *(ushort4*)(p.outb + (size_t)rowg * 768 + colg) = pk;
            } else if constexpr (EPI == 1 || EPI == 3) {
                const float* hi = p.hin + tokbase + colg;
                float* ho = p.hout + tokbase + colg;
                const float4 r = *(const float4*)hi;
                float4 o;
                o.x = r.x + t.x + bi.x;
                o.y = r.y + t.y + bi.y;
                o.z = r.z + t.z + bi.z;
                o.w = r.w + t.w + bi.w;
                *(float4*)ho = o;
            } else if constexpr (EPI == 2) {
                float4 g4;
                g4.x = t.x + bi.x; g4.y = t.y + bi.y; g4.z = t.z + bi.z; g4.w = t.w + bi.w;
                ushort4 pk;
                pk.x = f2b(0.5f * g4.x * (1.0f + erff(g4.x * 0.7071067811865475f)));
                pk.y = f2b(0.5f * g4.y * (1.0f + erff(g4.y * 0.7071067811865475f)));
                pk.z = f2b(0.5f * g4.z * (1.0f + erff(g4.z * 0.7071067811865475f)));
                pk.w = f2b(0.5f * g4.w * (1.0f + erff(g4.w * 0.7071067811865475f)));
                *(ushort4*)(p.outb + (size_t)rowg * 1024 + colg) = pk;
            } else {
                *(float4*)(p.outf + (size_t)rowg * 512 + colg) = t;
            }
        }
    }
}

// ---------------- fused MLP: out = hin + b2 + gelu(A@W1+b1)@W2 ----------------
// v5: 32 tokens per wave (2 token groups) -> each weight fragment ds_read
// feeds 2 MFMAs (was 1:1; LDS-BW was the round-5 wall at MFMA:read 4.8:12cy).
// Block = 256 tokens, 8 waves; per-chunk LDS traffic per block unchanged but
// block count halves. Fragment-major weights (conflict-free lane-linear
// reads), swapped gemm1, in-register gelu, K-permuted W2 (wt2f). One barrier
// per chunk. Epilogue: 4 CF rounds of 64 rows (writers: wv>>1 == cc).
struct MlpP {
    const u16* A;      // [T][256] bf16 (LN2 output, linear tokens)
    const u16* W1t;    // fragment-major [16 chunks][8 kt][4 n][64 lane][8]
    const u16* W2t;    // fragment-major [16 chunks][2 kt][16 nt][64 lane][8]
    const float* b1;   // [1024]
    const float* b2;   // [256]
    const float* hin;  // residual in fp32
    float* hout;       // fp32 out
};

__global__ __launch_bounds__(512, 1) void mlp_fused_kernel(MlpP p)
{
    __shared__ __align__(16) char smem[131072]; // W1 dbuf 2x32K @0 | W2 dbuf 2x32K @65536
    float* CF = (float*)smem;                   // 64x260 f32 epilogue overlay (66560B)

    const int tid = threadIdx.x;
    const int lane = tid & 63;
    const int wv = tid >> 6;                    // 0..7
    const int l16 = lane & 15, quad = lane >> 4;
    const int tok0 = blockIdx.x * 256;
    const int wtok = wv * 32;                   // wave's 32 tokens (2 groups of 16)

    // ---- A fragments -> registers, both token groups ----
    bf16x8 afr0[8], afr1[8];
    #pragma unroll
    for (int kt = 0; kt < 8; kt++) {
        afr0[kt] = *(const bf16x8*)(p.A + (size_t)(tok0 + wtok + l16) * 256 + kt * 32 + quad * 8);
        afr1[kt] = *(const bf16x8*)(p.A + (size_t)(tok0 + wtok + 16 + l16) * 256 + kt * 32 + quad * 8);
    }

    f32x4 acc2a[16], acc2b[16];
    #pragma unroll
    for (int nt = 0; nt < 16; nt++) {
        acc2a[nt] = f32x4{0.f, 0.f, 0.f, 0.f};
        acc2b[nt] = f32x4{0.f, 0.f, 0.f, 0.f};
    }

    // ---- fragment-major staging: wave wv stages fragments wv*4..wv*4+3 ----
    auto stage = [&](int c) {
        const u16* w1g = p.W1t + (size_t)c * 16384;
        const u16* w2g = p.W2t + (size_t)c * 16384;
        u16* w1b = (u16*)(smem + (c & 1) * 32768);
        u16* w2b = (u16*)(smem + 65536 + (c & 1) * 32768);
        #pragma unroll
        for (int f = 0; f < 4; f++) {
            const int fr = wv * 4 + f;
            gl_lds16(w1g + fr * 512 + lane * 8, w1b + fr * 512);
            gl_lds16(w2g + fr * 512 + lane * 8, w2b + fr * 512);
        }
    };

    stage(0);
    __syncthreads();

    #pragma unroll 2
    for (int c = 0; c < 16; c++) {
        if (c + 1 < 16) stage(c + 1);   // prefetch into alternate buffer

        // hoist b1 loads (shared by both token groups; mid = n*16+quad*4+i)
        float b1v[4][4];
        #pragma unroll
        for (int n = 0; n < 4; n++)
            #pragma unroll
            for (int i = 0; i < 4; i++)
                b1v[n][i] = p.b1[c * 64 + n * 16 + quad * 4 + i];

        // ---- gemm1 (swapped): acc1{a,b}[n] = D[mid tile n][token] ----
        const u16* W1c = (const u16*)(smem + (c & 1) * 32768);
        f32x4 acc1a[4], acc1b[4];
        #pragma unroll
        for (int n = 0; n < 4; n++) {
            acc1a[n] = f32x4{0.f, 0.f, 0.f, 0.f};
            acc1b[n] = f32x4{0.f, 0.f, 0.f, 0.f};
        }
        #pragma unroll
        for (int kt = 0; kt < 8; kt++) {
            bf16x8 w1f[4];
            #pragma unroll
            for (int n = 0; n < 4; n++)
                w1f[n] = *(const bf16x8*)(W1c + (kt * 4 + n) * 512 + lane * 8);
            #pragma unroll
            for (int n = 0; n < 4; n++) {
                acc1a[n] = __builtin_amdgcn_mfma_f32_16x16x32_bf16(w1f[n], afr0[kt], acc1a[n], 0, 0, 0);
                acc1b[n] = __builtin_amdgcn_mfma_f32_16x16x32_bf16(w1f[n], afr1[kt], acc1b[n], 0, 0, 0);
            }
        }

        // ---- bias + gelu (exp form) -> packed A-fragments, both groups ----
        bf16x8 pa0a, pa1a, pa0b, pa1b;
        #pragma unroll
        for (int n = 0; n < 4; n++) {
            #pragma unroll
            for (int i = 0; i < 4; i++) {
                {
                    const float x = acc1a[n][i] + b1v[n][i];
                    const float u = x * (1.0f + 0.044715f * x * x);
                    const float em = __expf(-1.5957691216f * u);
                    const float g = x * __builtin_amdgcn_rcpf(1.0f + em);
                    if (n < 2) pa0a[(n & 1) * 4 + i] = (__bf16)g;
                    else       pa1a[(n & 1) * 4 + i] = (__bf16)g;
                }
                {
                    const float x = acc1b[n][i] + b1v[n][i];
                    const float u = x * (1.0f + 0.044715f * x * x);
                    const float em = __expf(-1.5957691216f * u);
                    const float g = x * __builtin_amdgcn_rcpf(1.0f + em);
                    if (n < 2) pa0b[(n & 1) * 4 + i] = (__bf16)g;
                    else       pa1b[(n & 1) * 4 + i] = (__bf16)g;
                }
            }
        }

        // ---- gemm2: acc2{a,b}[nt] += pa @ W2c (one w2f read -> 2 MFMAs) ----
        const u16* W2c = (const u16*)(smem + 65536 + (c & 1) * 32768);
        #pragma unroll
        for (int kt = 0; kt < 2; kt++) {
            const bf16x8 pka = kt ? pa1a : pa0a;
            const bf16x8 pkb = kt ? pa1b : pa0b;
            #pragma unroll
            for (int nt = 0; nt < 16; nt++) {
                const bf16x8 w2f = *(const bf16x8*)(W2c + (kt * 16 + nt) * 512 + lane * 8);
                acc2a[nt] = __builtin_amdgcn_mfma_f32_16x16x32_bf16(pka, w2f, acc2a[nt], 0, 0, 0);
                acc2b[nt] = __builtin_amdgcn_mfma_f32_16x16x32_bf16(pkb, w2f, acc2b[nt], 0, 0, 0);
            }
        }
        __syncthreads();   // buf[c&1] reads done; stage(c+1) drained (vmcnt0)
    }

    float b2v[16];
    #pragma unroll
    for (int nt = 0; nt < 16; nt++) b2v[nt] = p.b2[nt * 16 + l16];

    // ---- transposed epilogue: 4 chunks of 64 rows through CF (stride 260) ----
    // group a: token = wtok + quad*4 + i; group b: token = wtok + 16 + quad*4 + i.
    #pragma unroll
    for (int cc = 0; cc < 4; cc++) {
        __syncthreads();
        if ((wv >> 1) == cc) {
            const int rb = (wv & 1) * 32;
            #pragma unroll
            for (int nt = 0; nt < 16; nt++)
                #pragma unroll
                for (int i = 0; i < 4; i++) {
                    CF[(rb + quad * 4 + i) * 260 + nt * 16 + l16] = acc2a[nt][i] + b2v[nt];
                    CF[(rb + 16 + quad * 4 + i) * 260 + nt * 16 + l16] = acc2b[nt][i] + b2v[nt];
                }
        }
        __syncthreads();
        #pragma unroll
        for (int jj = 0; jj < 8; jj++) {
            const int idx = jj * 512 + tid;           // 0..4095
            const int row = idx >> 6, c4 = (idx & 63) << 2;
            const size_t g = (size_t)(tok0 + cc * 64 + row) * 256 + c4;
            const float4 t = *(const float4*)(CF + row * 260 + c4);
            const float4 r = *(const float4*)(p.hin + g);
            float4 o;
            o.x = t.x + r.x; o.y = t.y + r.y; o.z = t.z + r.z; o.w = t.w + r.w;
            *(float4*)(p.hout + g) = o;
        }
    }
}

// ---------------- MFMA attention: one block per (window, head) ----------------
__global__ __launch_bounds__(256, 2) void attn_mfma_kernel(
    const u16* __restrict__ qkv, u16* __restrict__ att,
    const float* __restrict__ rpbp, int D, int shifted, int w0g, int nwsh)
{
    __shared__ __align__(16) char smem[57856];
    u16* Qs = (u16*)smem;
    u16* Ks = (u16*)(smem + 18432);
    u16* Ps = (u16*)smem;
    u16* Vt = (u16*)(smem + 36864);
    float* rb = (float*)(smem + 54272);
    int* lbl = (int*)(smem + 56972);

    const int wloc = blockIdx.x;
    const int head = blockIdx.y;
    const int tid = threadIdx.x;
    const u16* base = qkv + (size_t)wloc * 98304;

    #pragma unroll
    for (int it = 0; it < 4; it++) {
        const int id = it * 256 + tid;
        const int row = id >> 3, oct = id & 7;
        const size_t ro = (size_t)row * 768 + head * 64 + oct * 8;
        *(uint4*)(Qs + row * 72 + oct * 8) = *(const uint4*)(base + ro);
        *(uint4*)(Ks + row * 72 + oct * 8) = *(const uint4*)(base + ro + 256);
        uint4 vv = *(const uint4*)(base + ro + 512);
        const u16* vp = (const u16*)&vv;
        #pragma unroll
        for (int q = 0; q < 8; q++) Vt[(oct * 8 + q) * 136 + row] = vp[q];
    }
    for (int j = tid; j < 675; j += 256) rb[j] = rpbp[j * 4 + head];
    if (tid < 128) {
        int lv = 0;
        if (shifted) {
            const int widx = w0g + wloc;
            const int rem = widx & ((1 << nwsh) - 1);
            const int d0 = rem >> 6, h0 = (rem >> 3) & 7, w0 = rem & 7;
            const int wd = tid >> 6, wh = (tid >> 3) & 7, ww = tid & 7;
            const int rd = (d0 < (D >> 1) - 1) ? 0 : (1 + wd);
            const int rh = (h0 < 7) ? 0 : (1 + (wh >= 4));
            const int rw = (w0 < 7) ? 0 : (1 + (ww >= 4));
            lv = rd * 9 + rh * 3 + rw;
        }
        lbl[tid] = lv;
    }
    __syncthreads();

    const int wq = tid >> 6;
    const int lane = tid & 63;
    const int l16 = lane & 15, quad = lane >> 4;
    const int myrow0 = wq * 32;

    f32x4 sc[2][8];
    #pragma unroll
    for (int mt = 0; mt < 2; mt++)
        #pragma unroll
        for (int nt = 0; nt < 8; nt++)
            sc[mt][nt] = f32x4{0.f, 0.f, 0.f, 0.f};
    #pragma unroll
    for (int kt = 0; kt < 2; kt++) {
        bf16x8 aq[2];
        #pragma unroll
        for (int mt = 0; mt < 2; mt++)
            aq[mt] = *(const bf16x8*)(Qs + (myrow0 + mt * 16 + l16) * 72 + kt * 32 + quad * 8);
        bf16x8 bk[8];
        #pragma unroll
        for (int nt = 0; nt < 8; nt++)
            bk[nt] = *(const bf16x8*)(Ks + (nt * 16 + l16) * 72 + kt * 32 + quad * 8);
        #pragma unroll
        for (int mt = 0; mt < 2; mt++)
            #pragma unroll
            for (int nt = 0; nt < 8; nt++)
                sc[mt][nt] = __builtin_amdgcn_mfma_f32_16x16x32_bf16(aq[mt], bk[nt], sc[mt][nt], 0, 0, 0);
    }

    float linv[2][4];
    #pragma unroll
    for (int mt = 0; mt < 2; mt++) {
        #pragma unroll
        for (int i = 0; i < 4; i++) {
            const int row = myrow0 + mt * 16 + quad * 4 + i;
            const int rbase = ((row >> 6) + 1) * 225 + (((row >> 3) & 7) + 7) * 15 + ((row & 7) + 7);
            const int lq = lbl[row];
            float mx = -1e30f;
            float sv[8];
            #pragma unroll
            for (int nt = 0; nt < 8; nt++) {
                const int col = nt * 16 + l16;
                float v = sc[mt][nt][i] + rb[rbase - (col >> 6) * 225 - ((col >> 3) & 7) * 15 - (col & 7)];
                if (shifted && lq != lbl[col]) v -= 100.0f;
                sv[nt] = v;
                mx = fmaxf(mx, v);
            }
            #pragma unroll
            for (int o = 1; o < 16; o <<= 1) mx = fmaxf(mx, __shfl_xor(mx, o));
            float l = 0.0f;
            #pragma unroll
            for (int nt = 0; nt < 8; nt++) {
                const float pp = __expf(sv[nt] - mx);
                sc[mt][nt][i] = pp;
                l += pp;
            }
            #pragma unroll
            for (int o = 1; o < 16; o <<= 1) l += __shfl_xor(l, o);
            linv[mt][i] = 1.0f / l;
        }
    }

    __syncthreads();
    #pragma unroll
    for (int mt = 0; mt < 2; mt++)
        #pragma unroll
        for (int nt = 0; nt < 8; nt++)
            #pragma unroll
            for (int i = 0; i < 4; i++)
                Ps[(myrow0 + mt * 16 + quad * 4 + i) * 136 + nt * 16 + l16] = f2b(sc[mt][nt][i]);

    f32x4 oc[2][4];
    #pragma unroll
    for (int mt = 0; mt < 2; mt++)
        #pragma unroll
        for (int nt = 0; nt < 4; nt++)
            oc[mt][nt] = f32x4{0.f, 0.f, 0.f, 0.f};
    #pragma unroll
    for (int kt = 0; kt < 4; kt++) {
        bf16x8 ap[2];
        #pragma unroll
        for (int mt = 0; mt < 2; mt++)
            ap[mt] = *(const bf16x8*)(Ps + (myrow0 + mt * 16 + l16) * 136 + kt * 32 + quad * 8);
        bf16x8 bv[4];
        #pragma unroll
        for (int nt = 0; nt < 4; nt++)
            bv[nt] = *(const bf16x8*)(Vt + (nt * 16 + l16) * 136 + kt * 32 + quad * 8);
        #pragma unroll
        for (int mt = 0; mt < 2; mt++)
            #pragma unroll
            for (int nt = 0; nt < 4; nt++)
                oc[mt][nt] = __builtin_amdgcn_mfma_f32_16x16x32_bf16(ap[mt], bv[nt], oc[mt][nt], 0, 0, 0);
    }

    #pragma unroll
    for (int mt = 0; mt < 2; mt++)
        #pragma unroll
        for (int nt = 0; nt < 4; nt++)
            #pragma unroll
            for (int i = 0; i < 4; i++) {
                const int row = myrow0 + mt * 16 + quad * 4 + i;
                const int col = nt * 16 + l16;
                att[(size_t)(wloc * 128 + row) * 256 + head * 64 + col] = f2b(oc[mt][nt][i] * linv[mt][i]);
            }
}

// ---------------- patch-expand LN + reorder ----------------
__global__ __launch_bounds__(256) void expand_ln_kernel(
    const float* __restrict__ sc, float* __restrict__ hout,
    const float* __restrict__ g, const float* __restrict__ bb,
    int it0, int typ)
{
    const int lane = threadIdx.x & 63;
    const int ot = blockIdx.x * 4 + (threadIdx.x >> 6);
    const int itl = ot >> 1, e = ot & 1;
    const float4 xv = *(const float4*)(sc + (size_t)itl * 512 + e * 256 + lane * 4);
    float s = xv.x + xv.y + xv.z + xv.w;
    float s2 = xv.x*xv.x + xv.y*xv.y + xv.z*xv.z + xv.w*xv.w;
    #pragma unroll
    for (int o = 32; o > 0; o >>= 1) { s += __shfl_xor(s, o); s2 += __shfl_xor(s2, o); }
    const float mu = s * 0.00390625f;
    const float var = s2 * 0.00390625f - mu * mu;
    const float rs = 1.0f / sqrtf(var + 1e-5f);
    const int c0 = lane * 4;
    const float4 gv = *(const float4*)(g + c0);
    const float4 bv = *(const float4*)(bb + c0);
    float4 y;
    y.x = (xv.x - mu) * rs * gv.x + bv.x;
    y.y = (xv.y - mu) * rs * gv.y + bv.y;
    y.z = (xv.z - mu) * rs * gv.z + bv.z;
    y.w = (xv.w - mu) * rs * gv.w + bv.w;
    const int it = it0 + itl;
    size_t otg;
    if (typ == 0) {
        const int b = it >> 14, rr = it & 16383;
        const int t = rr >> 13, v = (rr >> 12) & 1, l = rr & 4095;
        otg = (size_t)(((b * 2 + t) * 4 + v * 2 + e) * 4096 + l);
    } else {
        const int b = it >> 15, rr = it & 32767;
        const int t = rr >> 14, v2 = (rr >> 12) & 3, l = rr & 4095;
        otg = (size_t)(((b * 4 + t * 2 + e) * 4 + v2) * 4096 + l);
    }
    *(float4*)(hout + otg * 256 + c0) = y;
}

// ---------------- host ----------------
extern "C" void kernel_launch(void* const* d_in, const int* in_sizes, int n_in,
                              void* d_out, int out_size, void* d_ws, size_t ws_size,
                              hipStream_t stream)
{
    const float* x      = (const float*)d_in[0];
    const float* n1w    = (const float*)d_in[1];
    const float* n1b    = (const float*)d_in[2];
    const float* qkv_w  = (const float*)d_in[3];
    const float* qkv_b  = (const float*)d_in[4];
    const float* rpb    = (const float*)d_in[5];
    const float* proj_w = (const float*)d_in[6];
    const float* proj_b = (const float*)d_in[7];
    const float* n2w    = (const float*)d_in[8];
    const float* n2b    = (const float*)d_in[9];
    const float* mlp1_w = (const float*)d_in[10];
    const float* mlp1_b = (const float*)d_in[11];
    const float* mlp2_w = (const float*)d_in[12];
    const float* mlp2_b = (const float*)d_in[13];
    const float* expv_w = (const float*)d_in[14];
    const float* expv_nw= (const float*)d_in[15];
    const float* expv_nb= (const float*)d_in[16];
    const float* expt_w = (const float*)d_in[17];
    const float* expt_nw= (const float*)d_in[18];
    const float* expt_nb= (const float*)d_in[19];
    (void)in_sizes; (void)n_in; (void)out_size;

    if (ws_size < 352321536ULL) return;

    char* ws = (char*)d_ws;
    float* h    = (float*)ws;
    u16*  winb  = (u16*)(ws + 134217728LL);
    u16*  att   = (u16*)(ws + 134217728LL + 67108864LL);
    char* scr   = ws + 134217728LL + 2LL * 67108864LL;
    u16*  scrb  = (u16*)scr;
    float* scrf = (float*)scr;
    u16* qkvT   = (u16*)(ws + 134217728LL + 3LL * 67108864LL);
    u16* projT  = qkvT + 6 * 768 * 256;
    u16* mlp1T  = projT + 6 * 256 * 256;
    u16* mlp2T  = mlp1T + 6 * 1024 * 256;
    u16* expvT  = mlp2T + 6 * 256 * 1024;
    u16* exptT  = expvT + 512 * 256;

    wt_kernel<<<dim3(768, 6), 256, 0, stream>>>(qkv_w, qkvT, 256, 768);
    wt_kernel<<<dim3(256, 6), 256, 0, stream>>>(proj_w, projT, 256, 256);
    wt1f_kernel<<<dim3(1024, 6), 256, 0, stream>>>(mlp1_w, mlp1T);
    wt2f_kernel<<<dim3(1024, 6), 256, 0, stream>>>(mlp2_w, mlp2T);
    wt_kernel<<<dim3(512, 1), 256, 0, stream>>>(expv_w, expvT, 256, 512);
    wt_kernel<<<dim3(512, 1), 256, 0, stream>>>(expt_w, exptT, 256, 512);
    hipMemcpyAsync(h, x, 33554432ULL, hipMemcpyDeviceToDevice, stream);

    for (int s = 0; s < 3; s++) {
        const int D = 4 << s;
        const int dsh = 2 + s;
        const int nwsh = dsh + 5;
        const int tokens = 2 * D * 4096;
        const int nch = tokens / 32768;
        for (int j = 0; j < 2; j++) {
            const int i = 2 * s + j;
            ln_kernel<<<dim3(tokens / 4), 256, 0, stream>>>(h, winb, n1w + i * 256, n1b + i * 256, D, dsh, j, 0);
            for (int c = 0; c < nch; c++) {
                GemmP gq{};
                gq.A = winb + (size_t)c * 32768 * 256;
                gq.Bt = qkvT + (size_t)i * 768 * 256;
                gq.K = 256; gq.bias = qkv_b + i * 768; gq.outb = scrb;
                gemm_kernel<0><<<dim3(256, 6), 256, 0, stream>>>(gq);
                attn_mfma_kernel<<<dim3(256, 4), 256, 0, stream>>>(scrb, att + (size_t)c * 32768 * 256,
                                                                   rpb + i * 675 * 4, D, j, c * 256, nwsh);
            }
            GemmP gp{};
            gp.A = att; gp.Bt = projT + (size_t)i * 256 * 256; gp.K = 256;
            gp.bias = proj_b + i * 256; gp.hin = h; gp.hout = h;
            gp.D = D; gp.shifted = j; gp.nwsh = nwsh;
            gemm_kernel<1><<<dim3(tokens / 128, 2), 256, 0, stream>>>(gp);
            ln_kernel<<<dim3(tokens / 4), 256, 0, stream>>>(h, winb, n2w + i * 256, n2b + i * 256, D, dsh, 0, 1);
            MlpP mp{};
            mp.A = winb;
            mp.W1t = mlp1T + (size_t)i * 262144;
            mp.W2t = mlp2T + (size_t)i * 262144;
            mp.b1 = mlp1_b + i * 1024;
            mp.b2 = mlp2_b + i * 256;
            mp.hin = h;
            mp.hout = (s == 2 && j == 1) ? (float*)d_out : h;
            mlp_fused_kernel<<<dim3(tokens / 256), 512, 0, stream>>>(mp);
        }
        if (s < 2) {
            const int ntok = tokens;
            cast_kernel<<<dim3(ntok * 64 / 256), 256, 0, stream>>>(h, winb, ntok * 64);
            const u16* eT = (s == 0) ? expvT : exptT;
            const float* eg = (s == 0) ? expv_nw : expt_nw;
            const float* eb = (s == 0) ? expv_nb : expt_nb;
            for (int c = 0; c < ntok / 32768; c++) {
                GemmP ge{};
                ge.A = winb + (size_t)c * 32768 * 256; ge.Bt = eT; ge.K = 256; ge.outf = scrf;
                gemm_kernel<4><<<dim3(256, 4), 256, 0, stream>>>(ge);
                expand_ln_kernel<<<dim3(16384), 256, 0, stream>>>(scrf, h, eg, eb, c * 32768, s);
            }
        }
    }
}

// Round 7
// 2581.552 us; speedup vs baseline: 1.0074x; 1.0074x over previous
//
#include <hip/hip_runtime.h>

typedef __bf16 bf16x8 __attribute__((ext_vector_type(8)));
typedef float f32x4 __attribute__((ext_vector_type(4)));
typedef unsigned short u16;
typedef unsigned int u32;

// ---------------- helpers ----------------
__device__ __forceinline__ u16 f2b(float f) {
    union { float f; u32 u; } v; v.f = f;
    u32 r = v.u + 0x7fffu + ((v.u >> 16) & 1u);
    return (u16)(r >> 16);
}
__device__ __forceinline__ float b2f(u16 u) {
    union { u32 u; float f; } v; v.u = ((u32)u) << 16; return v.f;
}
__device__ __forceinline__ void gl_lds16(const u16* g, u16* l) {
    __builtin_amdgcn_global_load_lds(
        (const __attribute__((address_space(1))) void*)g,
        (__attribute__((address_space(3))) void*)l, 16, 0, 0);
}

// ---------------- LN (+shift+window-partition) ----------------
__global__ __launch_bounds__(256) void ln_kernel(
    const float* __restrict__ h, u16* __restrict__ out,
    const float* __restrict__ g, const float* __restrict__ bb,
    int D, int dsh, int shifted, int mode)
{
    const int lane = threadIdx.x & 63;
    const int t = blockIdx.x * 4 + (threadIdx.x >> 6);
    const float4 xv = *(const float4*)(h + (size_t)t * 256 + lane * 4);
    float s = xv.x + xv.y + xv.z + xv.w;
    float s2 = xv.x*xv.x + xv.y*xv.y + xv.z*xv.z + xv.w*xv.w;
    #pragma unroll
    for (int o = 32; o > 0; o >>= 1) { s += __shfl_xor(s, o); s2 += __shfl_xor(s2, o); }
    const float mu = s * 0.00390625f;
    const float var = s2 * 0.00390625f - mu * mu;
    const float rs = 1.0f / sqrtf(var + 1e-5f);
    const int c0 = lane * 4;
    const float4 gv = *(const float4*)(g + c0);
    const float4 bv = *(const float4*)(bb + c0);
    ushort4 o4;
    o4.x = f2b((xv.x - mu) * rs * gv.x + bv.x);
    o4.y = f2b((xv.y - mu) * rs * gv.y + bv.y);
    o4.z = f2b((xv.z - mu) * rs * gv.z + bv.z);
    o4.w = f2b((xv.w - mu) * rs * gv.w + bv.w);
    size_t oidx;
    if (mode == 1) {
        oidx = (size_t)t * 256 + c0;
    } else {
        const int b = t >> (dsh + 12);
        const int rem = t & ((1 << (dsh + 12)) - 1);
        int d = rem >> 12;
        const int l = rem & 4095;
        int hh = l >> 6, ww = l & 63;
        if (shifted) { d = d ? d - 1 : D - 1; hh = (hh - 4) & 63; ww = (ww - 4) & 63; }
        const int widx = (b << (dsh + 5)) + ((d >> 1) << 6) + ((hh >> 3) << 3) + (ww >> 3);
        const int n = ((d & 1) << 6) + ((hh & 7) << 3) + (ww & 7);
        oidx = ((size_t)(widx * 128 + n)) * 256 + c0;
    }
    *(ushort4*)(out + oidx) = o4;
}

// ---------------- fp32 -> bf16 cast ----------------
__global__ __launch_bounds__(256) void cast_kernel(const float* __restrict__ in, u16* __restrict__ out, int n4)
{
    const int i = blockIdx.x * 256 + threadIdx.x;
    if (i >= n4) return;
    const float4 v = ((const float4*)in)[i];
    ushort4 o; o.x = f2b(v.x); o.y = f2b(v.y); o.z = f2b(v.z); o.w = f2b(v.w);
    ((ushort4*)out)[i] = o;
}

// ---------------- weight transpose+cast ----------------
__global__ __launch_bounds__(256) void wt_kernel(const float* __restrict__ src, u16* __restrict__ dst, int K, int N)
{
    const size_t base = (size_t)blockIdx.y * K * N;
    const int idx = blockIdx.x * 256 + threadIdx.x;
    const int k = idx / N, n = idx - k * N;
    dst[base + (size_t)n * K + k] = f2b(src[base + idx]);
}

// ---------------- W1 fragment-major pack ----------------
// dst[((c*8+kt)*4+n)*512 + lane*8 + e] = W1[kt*32 + (lane>>4)*8 + e][c*64 + n*16 + (lane&15)]
__global__ __launch_bounds__(256) void wt1f_kernel(const float* __restrict__ src, u16* __restrict__ dst)
{
    const size_t base = (size_t)blockIdx.y * 262144;
    const int t = blockIdx.x * 256 + threadIdx.x;   // 0..262143
    const int e = t & 7, lane = (t >> 3) & 63, n = (t >> 9) & 3, kt = (t >> 11) & 7, c = t >> 14;
    const int k = kt * 32 + (lane >> 4) * 8 + e;
    const int mid = c * 64 + n * 16 + (lane & 15);
    dst[base + t] = f2b(src[base + (size_t)k * 1024 + mid]);
}

// ---------------- W2 fragment-major pack (with K-permutation m()) ----------------
// dst[((c*2+kt)*16+nt)*512 + lane*8 + e] = W2[c*64 + m(kt,quad,e)][nt*16 + (lane&15)]
__global__ __launch_bounds__(256) void wt2f_kernel(const float* __restrict__ src, u16* __restrict__ dst)
{
    const size_t base = (size_t)blockIdx.y * 262144;
    const int t = blockIdx.x * 256 + threadIdx.x;
    const int e = t & 7, lane = (t >> 3) & 63, nt = (t >> 9) & 15, kt = (t >> 13) & 1, c = t >> 14;
    const int q = lane >> 4;
    const int mid = (2 * kt + (e >> 2)) * 16 + q * 4 + (e & 3);
    const int k = c * 64 + mid;
    const int out = nt * 16 + (lane & 15);
    dst[base + t] = f2b(src[base + (size_t)k * 256 + out]);
}

// ---------------- MFMA bf16 GEMM, 128x128 tile ----------------
struct GemmP {
    const u16* A; const u16* Bt;
    int K;
    const float* bias;
    u16* outb;
    float* outf;
    const float* hin; float* hout;
    int D, shifted, nwsh, row_off;
};

template <int EPI>
__global__ __launch_bounds__(256, 2) void gemm_kernel(GemmP p)
{
    __shared__ __align__(16) char smem[33792];  // 2x(As 8K | Bs 8K); CF 64x132 f32 overlay
    float* CF = (float*)smem;

    const int tid = threadIdx.x;
    const int m0 = blockIdx.x * 128, n0 = blockIdx.y * 128;
    const int K = p.K;
    const int lane = tid & 63;
    const int wv = tid >> 6;
    const int wm = (wv & 1) * 64, wn = (wv >> 1) * 64;
    const int l16 = lane & 15, quad = lane >> 4;

    f32x4 acc[4][4];
    #pragma unroll
    for (int a = 0; a < 4; a++)
        #pragma unroll
        for (int b = 0; b < 4; b++)
            acc[a][b] = f32x4{0.f, 0.f, 0.f, 0.f};

    const int lrow = lane >> 2;
    const int c16s = (lane & 3) ^ (lrow & 3);
    const int rA0 = wv * 16;
    const u16* Ag = p.A + (size_t)(m0 + rA0 + lrow) * K + c16s * 8;
    const u16* Bg = p.Bt + (size_t)(n0 + rA0 + lrow) * K + c16s * 8;
    const size_t j64 = (size_t)64 * K;
    const int fslot = (quad ^ (l16 & 3)) * 8;

    {
        u16* Al = (u16*)smem + rA0 * 32;
        u16* Bl = (u16*)(smem + 8192) + rA0 * 32;
        gl_lds16(Ag, Al);
        gl_lds16(Ag + j64, Al + 64 * 32);
        gl_lds16(Bg, Bl);
        gl_lds16(Bg + j64, Bl + 64 * 32);
    }
    __syncthreads();

    int kb = 0;
    for (int k0 = 0; k0 < K; k0 += 32, kb ^= 1) {
        if (k0 + 32 < K) {
            char* nb = smem + (kb ^ 1) * 16384;
            u16* Al = (u16*)nb + rA0 * 32;
            u16* Bl = (u16*)(nb + 8192) + rA0 * 32;
            gl_lds16(Ag + k0 + 32, Al);
            gl_lds16(Ag + j64 + k0 + 32, Al + 64 * 32);
            gl_lds16(Bg + k0 + 32, Bl);
            gl_lds16(Bg + j64 + k0 + 32, Bl + 64 * 32);
        }
        const u16* As = (const u16*)(smem + kb * 16384);
        const u16* Bs = (const u16*)(smem + kb * 16384 + 8192);
        bf16x8 af[4], bfr[4];
        #pragma unroll
        for (int mt = 0; mt < 4; mt++) af[mt] = *(const bf16x8*)(As + (wm + mt * 16 + l16) * 32 + fslot);
        #pragma unroll
        for (int nt = 0; nt < 4; nt++) bfr[nt] = *(const bf16x8*)(Bs + (wn + nt * 16 + l16) * 32 + fslot);
        #pragma unroll
        for (int mt = 0; mt < 4; mt++)
            #pragma unroll
            for (int nt = 0; nt < 4; nt++)
                acc[mt][nt] = __builtin_amdgcn_mfma_f32_16x16x32_bf16(af[mt], bfr[nt], acc[mt][nt], 0, 0, 0);
        __syncthreads();
    }

    const int crow = tid >> 2;
    const int p4 = (tid & 3) * 4;
    #pragma unroll
    for (int c = 0; c < 2; c++) {
        if (c) __syncthreads();
        if ((wv & 1) == c) {
            #pragma unroll
            for (int mt = 0; mt < 4; mt++)
                #pragma unroll
                for (int nt = 0; nt < 4; nt++)
                    #pragma unroll
                    for (int i = 0; i < 4; i++)
                        CF[(mt * 16 + quad * 4 + i) * 132 + wn + nt * 16 + l16] = acc[mt][nt][i];
        }
        __syncthreads();
        const int rowg = m0 + c * 64 + crow;
        size_t tokbase = 0;
        if constexpr (EPI == 1) {
            const int widx = rowg >> 7, n = rowg & 127;
            const int b = widx >> p.nwsh, rem = widx & ((1 << p.nwsh) - 1);
            int dd = ((rem >> 6) << 1) + (n >> 6);
            int hh = (((rem >> 3) & 7) << 3) + ((n >> 3) & 7);
            int ww = ((rem & 7) << 3) + (n & 7);
            if (p.shifted) { dd = (dd + 1 == p.D) ? 0 : dd + 1; hh = (hh + 4) & 63; ww = (ww + 4) & 63; }
            tokbase = ((size_t)((b * p.D + dd) * 4096 + hh * 64 + ww)) * 256;
        } else if constexpr (EPI == 3) {
            tokbase = (size_t)(p.row_off + rowg) * 256;
        }
        #pragma unroll
        for (int j = 0; j < 8; j++) {
            const int colf = j * 16 + p4;
            const int colg = n0 + colf;
            const float4 t = *(const float4*)(CF + crow * 132 + colf);
            const float4 bi = (EPI <= 3) ? *(const float4*)(p.bias + colg) : float4{0.f,0.f,0.f,0.f};
            if constexpr (EPI == 0) {
                const float sc = (colg < 256) ? 0.125f : 1.0f;
                ushort4 pk;
                pk.x = f2b((t.x + bi.x) * sc);
                pk.y = f2b((t.y + bi.y) * sc);
                pk.z = f2b((t.z + bi.z) * sc);
                pk.w = f2b((t.w + bi.w) * sc);
                *(ushort4*)(p.outb + (size_t)rowg * 768 + colg) = pk;
            } else if constexpr (EPI == 1 || EPI == 3) {
                const float* hi = p.hin + tokbase + colg;
                float* ho = p.hout + tokbase + colg;
                const float4 r = *(const float4*)hi;
                float4 o;
                o.x = r.x + t.x + bi.x;
                o.y = r.y + t.y + bi.y;
                o.z = r.z + t.z + bi.z;
                o.w = r.w + t.w + bi.w;
                *(float4*)ho = o;
            } else if constexpr (EPI == 2) {
                float4 g4;
                g4.x = t.x + bi.x; g4.y = t.y + bi.y; g4.z = t.z + bi.z; g4.w = t.w + bi.w;
                ushort4 pk;
                pk.x = f2b(0.5f * g4.x * (1.0f + erff(g4.x * 0.7071067811865475f)));
                pk.y = f2b(0.5f * g4.y * (1.0f + erff(g4.y * 0.7071067811865475f)));
                pk.z = f2b(0.5f * g4.z * (1.0f + erff(g4.z * 0.7071067811865475f)));
                pk.w = f2b(0.5f * g4.w * (1.0f + erff(g4.w * 0.7071067811865475f)));
                *(ushort4*)(p.outb + (size_t)rowg * 1024 + colg) = pk;
            } else {
                *(float4*)(p.outf + (size_t)rowg * 512 + colg) = t;
            }
        }
    }
}

// ---------------- fused MLP: out = hin + b2 + gelu(A@W1+b1)@W2 ----------------
// v6 = v5 structure (32 tokens/wave, 2 token groups, 1:2 weight-read:MFMA)
// with the register-spill fixed: __launch_bounds__(512,2) sets the explicit
// 256-VGPR budget (round-6's (512,1) led the compiler to a 128-reg target ->
// ~108MB scratch traffic, WRITE_SIZE 131->242MB), and b1 is loaded per-n as a
// transient float4 inside the gelu loop instead of a 16-reg pre-gemm1 hoist.
struct MlpP {
    const u16* A;      // [T][256] bf16 (LN2 output, linear tokens)
    const u16* W1t;    // fragment-major [16 chunks][8 kt][4 n][64 lane][8]
    const u16* W2t;    // fragment-major [16 chunks][2 kt][16 nt][64 lane][8]
    const float* b1;   // [1024]
    const float* b2;   // [256]
    const float* hin;  // residual in fp32
    float* hout;       // fp32 out
};

__global__ __launch_bounds__(512, 2) void mlp_fused_kernel(MlpP p)
{
    __shared__ __align__(16) char smem[131072]; // W1 dbuf 2x32K @0 | W2 dbuf 2x32K @65536
    float* CF = (float*)smem;                   // 64x260 f32 epilogue overlay (66560B)

    const int tid = threadIdx.x;
    const int lane = tid & 63;
    const int wv = tid >> 6;                    // 0..7
    const int l16 = lane & 15, quad = lane >> 4;
    const int tok0 = blockIdx.x * 256;
    const int wtok = wv * 32;                   // wave's 32 tokens (2 groups of 16)

    // ---- A fragments -> registers, both token groups ----
    bf16x8 afr0[8], afr1[8];
    #pragma unroll
    for (int kt = 0; kt < 8; kt++) {
        afr0[kt] = *(const bf16x8*)(p.A + (size_t)(tok0 + wtok + l16) * 256 + kt * 32 + quad * 8);
        afr1[kt] = *(const bf16x8*)(p.A + (size_t)(tok0 + wtok + 16 + l16) * 256 + kt * 32 + quad * 8);
    }

    f32x4 acc2a[16], acc2b[16];
    #pragma unroll
    for (int nt = 0; nt < 16; nt++) {
        acc2a[nt] = f32x4{0.f, 0.f, 0.f, 0.f};
        acc2b[nt] = f32x4{0.f, 0.f, 0.f, 0.f};
    }

    // ---- fragment-major staging: wave wv stages fragments wv*4..wv*4+3 ----
    auto stage = [&](int c) {
        const u16* w1g = p.W1t + (size_t)c * 16384;
        const u16* w2g = p.W2t + (size_t)c * 16384;
        u16* w1b = (u16*)(smem + (c & 1) * 32768);
        u16* w2b = (u16*)(smem + 65536 + (c & 1) * 32768);
        #pragma unroll
        for (int f = 0; f < 4; f++) {
            const int fr = wv * 4 + f;
            gl_lds16(w1g + fr * 512 + lane * 8, w1b + fr * 512);
            gl_lds16(w2g + fr * 512 + lane * 8, w2b + fr * 512);
        }
    };

    stage(0);
    __syncthreads();

    #pragma unroll 2
    for (int c = 0; c < 16; c++) {
        if (c + 1 < 16) stage(c + 1);   // prefetch into alternate buffer

        // ---- gemm1 (swapped): acc1{a,b}[n] = D[mid tile n][token] ----
        const u16* W1c = (const u16*)(smem + (c & 1) * 32768);
        f32x4 acc1a[4], acc1b[4];
        #pragma unroll
        for (int n = 0; n < 4; n++) {
            acc1a[n] = f32x4{0.f, 0.f, 0.f, 0.f};
            acc1b[n] = f32x4{0.f, 0.f, 0.f, 0.f};
        }
        #pragma unroll
        for (int kt = 0; kt < 8; kt++) {
            bf16x8 w1f[4];
            #pragma unroll
            for (int n = 0; n < 4; n++)
                w1f[n] = *(const bf16x8*)(W1c + (kt * 4 + n) * 512 + lane * 8);
            #pragma unroll
            for (int n = 0; n < 4; n++) {
                acc1a[n] = __builtin_amdgcn_mfma_f32_16x16x32_bf16(w1f[n], afr0[kt], acc1a[n], 0, 0, 0);
                acc1b[n] = __builtin_amdgcn_mfma_f32_16x16x32_bf16(w1f[n], afr1[kt], acc1b[n], 0, 0, 0);
            }
        }

        // ---- bias + gelu (exp form) -> packed A-fragments, both groups ----
        // b1 loaded per-n as a transient float4 (keeps peak VGPR below 256)
        bf16x8 pa0a, pa1a, pa0b, pa1b;
        #pragma unroll
        for (int n = 0; n < 4; n++) {
            const float4 b1q = *(const float4*)(p.b1 + c * 64 + n * 16 + quad * 4);
            #pragma unroll
            for (int i = 0; i < 4; i++) {
                const float b1i = (i == 0) ? b1q.x : (i == 1) ? b1q.y : (i == 2) ? b1q.z : b1q.w;
                {
                    const float x = acc1a[n][i] + b1i;
                    const float u = x * (1.0f + 0.044715f * x * x);
                    const float em = __expf(-1.5957691216f * u);
                    const float g = x * __builtin_amdgcn_rcpf(1.0f + em);
                    if (n < 2) pa0a[(n & 1) * 4 + i] = (__bf16)g;
                    else       pa1a[(n & 1) * 4 + i] = (__bf16)g;
                }
                {
                    const float x = acc1b[n][i] + b1i;
                    const float u = x * (1.0f + 0.044715f * x * x);
                    const float em = __expf(-1.5957691216f * u);
                    const float g = x * __builtin_amdgcn_rcpf(1.0f + em);
                    if (n < 2) pa0b[(n & 1) * 4 + i] = (__bf16)g;
                    else       pa1b[(n & 1) * 4 + i] = (__bf16)g;
                }
            }
        }

        // ---- gemm2: acc2{a,b}[nt] += pa @ W2c (one w2f read -> 2 MFMAs) ----
        const u16* W2c = (const u16*)(smem + 65536 + (c & 1) * 32768);
        #pragma unroll
        for (int kt = 0; kt < 2; kt++) {
            const bf16x8 pka = kt ? pa1a : pa0a;
            const bf16x8 pkb = kt ? pa1b : pa0b;
            #pragma unroll
            for (int nt = 0; nt < 16; nt++) {
                const bf16x8 w2f = *(const bf16x8*)(W2c + (kt * 16 + nt) * 512 + lane * 8);
                acc2a[nt] = __builtin_amdgcn_mfma_f32_16x16x32_bf16(pka, w2f, acc2a[nt], 0, 0, 0);
                acc2b[nt] = __builtin_amdgcn_mfma_f32_16x16x32_bf16(pkb, w2f, acc2b[nt], 0, 0, 0);
            }
        }
        __syncthreads();   // buf[c&1] reads done; stage(c+1) drained (vmcnt0)
    }

    float b2v[16];
    #pragma unroll
    for (int nt = 0; nt < 16; nt++) b2v[nt] = p.b2[nt * 16 + l16];

    // ---- transposed epilogue: 4 chunks of 64 rows through CF (stride 260) ----
    // group a: token = wtok + quad*4 + i; group b: token = wtok + 16 + quad*4 + i.
    #pragma unroll
    for (int cc = 0; cc < 4; cc++) {
        __syncthreads();
        if ((wv >> 1) == cc) {
            const int rb = (wv & 1) * 32;
            #pragma unroll
            for (int nt = 0; nt < 16; nt++)
                #pragma unroll
                for (int i = 0; i < 4; i++) {
                    CF[(rb + quad * 4 + i) * 260 + nt * 16 + l16] = acc2a[nt][i] + b2v[nt];
                    CF[(rb + 16 + quad * 4 + i) * 260 + nt * 16 + l16] = acc2b[nt][i] + b2v[nt];
                }
        }
        __syncthreads();
        #pragma unroll
        for (int jj = 0; jj < 8; jj++) {
            const int idx = jj * 512 + tid;           // 0..4095
            const int row = idx >> 6, c4 = (idx & 63) << 2;
            const size_t g = (size_t)(tok0 + cc * 64 + row) * 256 + c4;
            const float4 t = *(const float4*)(CF + row * 260 + c4);
            const float4 r = *(const float4*)(p.hin + g);
            float4 o;
            o.x = t.x + r.x; o.y = t.y + r.y; o.z = t.z + r.z; o.w = t.w + r.w;
            *(float4*)(p.hout + g) = o;
        }
    }
}

// ---------------- MFMA attention: one block per (window, head) ----------------
__global__ __launch_bounds__(256, 2) void attn_mfma_kernel(
    const u16* __restrict__ qkv, u16* __restrict__ att,
    const float* __restrict__ rpbp, int D, int shifted, int w0g, int nwsh)
{
    __shared__ __align__(16) char smem[57856];
    u16* Qs = (u16*)smem;
    u16* Ks = (u16*)(smem + 18432);
    u16* Ps = (u16*)smem;
    u16* Vt = (u16*)(smem + 36864);
    float* rb = (float*)(smem + 54272);
    int* lbl = (int*)(smem + 56972);

    const int wloc = blockIdx.x;
    const int head = blockIdx.y;
    const int tid = threadIdx.x;
    const u16* base = qkv + (size_t)wloc * 98304;

    #pragma unroll
    for (int it = 0; it < 4; it++) {
        const int id = it * 256 + tid;
        const int row = id >> 3, oct = id & 7;
        const size_t ro = (size_t)row * 768 + head * 64 + oct * 8;
        *(uint4*)(Qs + row * 72 + oct * 8) = *(const uint4*)(base + ro);
        *(uint4*)(Ks + row * 72 + oct * 8) = *(const uint4*)(base + ro + 256);
        uint4 vv = *(const uint4*)(base + ro + 512);
        const u16* vp = (const u16*)&vv;
        #pragma unroll
        for (int q = 0; q < 8; q++) Vt[(oct * 8 + q) * 136 + row] = vp[q];
    }
    for (int j = tid; j < 675; j += 256) rb[j] = rpbp[j * 4 + head];
    if (tid < 128) {
        int lv = 0;
        if (shifted) {
            const int widx = w0g + wloc;
            const int rem = widx & ((1 << nwsh) - 1);
            const int d0 = rem >> 6, h0 = (rem >> 3) & 7, w0 = rem & 7;
            const int wd = tid >> 6, wh = (tid >> 3) & 7, ww = tid & 7;
            const int rd = (d0 < (D >> 1) - 1) ? 0 : (1 + wd);
            const int rh = (h0 < 7) ? 0 : (1 + (wh >= 4));
            const int rw = (w0 < 7) ? 0 : (1 + (ww >= 4));
            lv = rd * 9 + rh * 3 + rw;
        }
        lbl[tid] = lv;
    }
    __syncthreads();

    const int wq = tid >> 6;
    const int lane = tid & 63;
    const int l16 = lane & 15, quad = lane >> 4;
    const int myrow0 = wq * 32;

    f32x4 sc[2][8];
    #pragma unroll
    for (int mt = 0; mt < 2; mt++)
        #pragma unroll
        for (int nt = 0; nt < 8; nt++)
            sc[mt][nt] = f32x4{0.f, 0.f, 0.f, 0.f};
    #pragma unroll
    for (int kt = 0; kt < 2; kt++) {
        bf16x8 aq[2];
        #pragma unroll
        for (int mt = 0; mt < 2; mt++)
            aq[mt] = *(const bf16x8*)(Qs + (myrow0 + mt * 16 + l16) * 72 + kt * 32 + quad * 8);
        bf16x8 bk[8];
        #pragma unroll
        for (int nt = 0; nt < 8; nt++)
            bk[nt] = *(const bf16x8*)(Ks + (nt * 16 + l16) * 72 + kt * 32 + quad * 8);
        #pragma unroll
        for (int mt = 0; mt < 2; mt++)
            #pragma unroll
            for (int nt = 0; nt < 8; nt++)
                sc[mt][nt] = __builtin_amdgcn_mfma_f32_16x16x32_bf16(aq[mt], bk[nt], sc[mt][nt], 0, 0, 0);
    }

    float linv[2][4];
    #pragma unroll
    for (int mt = 0; mt < 2; mt++) {
        #pragma unroll
        for (int i = 0; i < 4; i++) {
            const int row = myrow0 + mt * 16 + quad * 4 + i;
            const int rbase = ((row >> 6) + 1) * 225 + (((row >> 3) & 7) + 7) * 15 + ((row & 7) + 7);
            const int lq = lbl[row];
            float mx = -1e30f;
            float sv[8];
            #pragma unroll
            for (int nt = 0; nt < 8; nt++) {
                const int col = nt * 16 + l16;
                float v = sc[mt][nt][i] + rb[rbase - (col >> 6) * 225 - ((col >> 3) & 7) * 15 - (col & 7)];
                if (shifted && lq != lbl[col]) v -= 100.0f;
                sv[nt] = v;
                mx = fmaxf(mx, v);
            }
            #pragma unroll
            for (int o = 1; o < 16; o <<= 1) mx = fmaxf(mx, __shfl_xor(mx, o));
            float l = 0.0f;
            #pragma unroll
            for (int nt = 0; nt < 8; nt++) {
                const float pp = __expf(sv[nt] - mx);
                sc[mt][nt][i] = pp;
                l += pp;
            }
            #pragma unroll
            for (int o = 1; o < 16; o <<= 1) l += __shfl_xor(l, o);
            linv[mt][i] = 1.0f / l;
        }
    }

    __syncthreads();
    #pragma unroll
    for (int mt = 0; mt < 2; mt++)
        #pragma unroll
        for (int nt = 0; nt < 8; nt++)
            #pragma unroll
            for (int i = 0; i < 4; i++)
                Ps[(myrow0 + mt * 16 + quad * 4 + i) * 136 + nt * 16 + l16] = f2b(sc[mt][nt][i]);

    f32x4 oc[2][4];
    #pragma unroll
    for (int mt = 0; mt < 2; mt++)
        #pragma unroll
        for (int nt = 0; nt < 4; nt++)
            oc[mt][nt] = f32x4{0.f, 0.f, 0.f, 0.f};
    #pragma unroll
    for (int kt = 0; kt < 4; kt++) {
        bf16x8 ap[2];
        #pragma unroll
        for (int mt = 0; mt < 2; mt++)
            ap[mt] = *(const bf16x8*)(Ps + (myrow0 + mt * 16 + l16) * 136 + kt * 32 + quad * 8);
        bf16x8 bv[4];
        #pragma unroll
        for (int nt = 0; nt < 4; nt++)
            bv[nt] = *(const bf16x8*)(Vt + (nt * 16 + l16) * 136 + kt * 32 + quad * 8);
        #pragma unroll
        for (int mt = 0; mt < 2; mt++)
            #pragma unroll
            for (int nt = 0; nt < 4; nt++)
                oc[mt][nt] = __builtin_amdgcn_mfma_f32_16x16x32_bf16(ap[mt], bv[nt], oc[mt][nt], 0, 0, 0);
    }

    #pragma unroll
    for (int mt = 0; mt < 2; mt++)
        #pragma unroll
        for (int nt = 0; nt < 4; nt++)
            #pragma unroll
            for (int i = 0; i < 4; i++) {
                const int row = myrow0 + mt * 16 + quad * 4 + i;
                const int col = nt * 16 + l16;
                att[(size_t)(wloc * 128 + row) * 256 + head * 64 + col] = f2b(oc[mt][nt][i] * linv[mt][i]);
            }
}

// ---------------- patch-expand LN + reorder ----------------
__global__ __launch_bounds__(256) void expand_ln_kernel(
    const float* __restrict__ sc, float* __restrict__ hout,
    const float* __restrict__ g, const float* __restrict__ bb,
    int it0, int typ)
{
    const int lane = threadIdx.x & 63;
    const int ot = blockIdx.x * 4 + (threadIdx.x >> 6);
    const int itl = ot >> 1, e = ot & 1;
    const float4 xv = *(const float4*)(sc + (size_t)itl * 512 + e * 256 + lane * 4);
    float s = xv.x + xv.y + xv.z + xv.w;
    float s2 = xv.x*xv.x + xv.y*xv.y + xv.z*xv.z + xv.w*xv.w;
    #pragma unroll
    for (int o = 32; o > 0; o >>= 1) { s += __shfl_xor(s, o); s2 += __shfl_xor(s2, o); }
    const float mu = s * 0.00390625f;
    const float var = s2 * 0.00390625f - mu * mu;
    const float rs = 1.0f / sqrtf(var + 1e-5f);
    const int c0 = lane * 4;
    const float4 gv = *(const float4*)(g + c0);
    const float4 bv = *(const float4*)(bb + c0);
    float4 y;
    y.x = (xv.x - mu) * rs * gv.x + bv.x;
    y.y = (xv.y - mu) * rs * gv.y + bv.y;
    y.z = (xv.z - mu) * rs * gv.z + bv.z;
    y.w = (xv.w - mu) * rs * gv.w + bv.w;
    const int it = it0 + itl;
    size_t otg;
    if (typ == 0) {
        const int b = it >> 14, rr = it & 16383;
        const int t = rr >> 13, v = (rr >> 12) & 1, l = rr & 4095;
        otg = (size_t)(((b * 2 + t) * 4 + v * 2 + e) * 4096 + l);
    } else {
        const int b = it >> 15, rr = it & 32767;
        const int t = rr >> 14, v2 = (rr >> 12) & 3, l = rr & 4095;
        otg = (size_t)(((b * 4 + t * 2 + e) * 4 + v2) * 4096 + l);
    }
    *(float4*)(hout + otg * 256 + c0) = y;
}

// ---------------- host ----------------
extern "C" void kernel_launch(void* const* d_in, const int* in_sizes, int n_in,
                              void* d_out, int out_size, void* d_ws, size_t ws_size,
                              hipStream_t stream)
{
    const float* x      = (const float*)d_in[0];
    const float* n1w    = (const float*)d_in[1];
    const float* n1b    = (const float*)d_in[2];
    const float* qkv_w  = (const float*)d_in[3];
    const float* qkv_b  = (const float*)d_in[4];
    const float* rpb    = (const float*)d_in[5];
    const float* proj_w = (const float*)d_in[6];
    const float* proj_b = (const float*)d_in[7];
    const float* n2w    = (const float*)d_in[8];
    const float* n2b    = (const float*)d_in[9];
    const float* mlp1_w = (const float*)d_in[10];
    const float* mlp1_b = (const float*)d_in[11];
    const float* mlp2_w = (const float*)d_in[12];
    const float* mlp2_b = (const float*)d_in[13];
    const float* expv_w = (const float*)d_in[14];
    const float* expv_nw= (const float*)d_in[15];
    const float* expv_nb= (const float*)d_in[16];
    const float* expt_w = (const float*)d_in[17];
    const float* expt_nw= (const float*)d_in[18];
    const float* expt_nb= (const float*)d_in[19];
    (void)in_sizes; (void)n_in; (void)out_size;

    if (ws_size < 352321536ULL) return;

    char* ws = (char*)d_ws;
    float* h    = (float*)ws;
    u16*  winb  = (u16*)(ws + 134217728LL);
    u16*  att   = (u16*)(ws + 134217728LL + 67108864LL);
    char* scr   = ws + 134217728LL + 2LL * 67108864LL;
    u16*  scrb  = (u16*)scr;
    float* scrf = (float*)scr;
    u16* qkvT   = (u16*)(ws + 134217728LL + 3LL * 67108864LL);
    u16* projT  = qkvT + 6 * 768 * 256;
    u16* mlp1T  = projT + 6 * 256 * 256;
    u16* mlp2T  = mlp1T + 6 * 1024 * 256;
    u16* expvT  = mlp2T + 6 * 256 * 1024;
    u16* exptT  = expvT + 512 * 256;

    wt_kernel<<<dim3(768, 6), 256, 0, stream>>>(qkv_w, qkvT, 256, 768);
    wt_kernel<<<dim3(256, 6), 256, 0, stream>>>(proj_w, projT, 256, 256);
    wt1f_kernel<<<dim3(1024, 6), 256, 0, stream>>>(mlp1_w, mlp1T);
    wt2f_kernel<<<dim3(1024, 6), 256, 0, stream>>>(mlp2_w, mlp2T);
    wt_kernel<<<dim3(512, 1), 256, 0, stream>>>(expv_w, expvT, 256, 512);
    wt_kernel<<<dim3(512, 1), 256, 0, stream>>>(expt_w, exptT, 256, 512);
    hipMemcpyAsync(h, x, 33554432ULL, hipMemcpyDeviceToDevice, stream);

    for (int s = 0; s < 3; s++) {
        const int D = 4 << s;
        const int dsh = 2 + s;
        const int nwsh = dsh + 5;
        const int tokens = 2 * D * 4096;
        const int nch = tokens / 32768;
        for (int j = 0; j < 2; j++) {
            const int i = 2 * s + j;
            ln_kernel<<<dim3(tokens / 4), 256, 0, stream>>>(h, winb, n1w + i * 256, n1b + i * 256, D, dsh, j, 0);
            for (int c = 0; c < nch; c++) {
                GemmP gq{};
                gq.A = winb + (size_t)c * 32768 * 256;
                gq.Bt = qkvT + (size_t)i * 768 * 256;
                gq.K = 256; gq.bias = qkv_b + i * 768; gq.outb = scrb;
                gemm_kernel<0><<<dim3(256, 6), 256, 0, stream>>>(gq);
                attn_mfma_kernel<<<dim3(256, 4), 256, 0, stream>>>(scrb, att + (size_t)c * 32768 * 256,
                                                                   rpb + i * 675 * 4, D, j, c * 256, nwsh);
            }
            GemmP gp{};
            gp.A = att; gp.Bt = projT + (size_t)i * 256 * 256; gp.K = 256;
            gp.bias = proj_b + i * 256; gp.hin = h; gp.hout = h;
            gp.D = D; gp.shifted = j; gp.nwsh = nwsh;
            gemm_kernel<1><<<dim3(tokens / 128, 2), 256, 0, stream>>>(gp);
            ln_kernel<<<dim3(tokens / 4), 256, 0, stream>>>(h, winb, n2w + i * 256, n2b + i * 256, D, dsh, 0, 1);
            MlpP mp{};
            mp.A = winb;
            mp.W1t = mlp1T + (size_t)i * 262144;
            mp.W2t = mlp2T + (size_t)i * 262144;
            mp.b1 = mlp1_b + i * 1024;
            mp.b2 = mlp2_b + i * 256;
            mp.hin = h;
            mp.hout = (s == 2 && j == 1) ? (float*)d_out : h;
            mlp_fused_kernel<<<dim3(tokens / 256), 512, 0, stream>>>(mp);
        }
        if (s < 2) {
            const int ntok = tokens;
            cast_kernel<<<dim3(ntok * 64 / 256), 256, 0, stream>>>(h, winb, ntok * 64);
            const u16* eT = (s == 0) ? expvT : exptT;
            const float* eg = (s == 0) ? expv_nw : expt_nw;
            const float* eb = (s == 0) ? expv_nb : expt_nb;
            for (int c = 0; c < ntok / 32768; c++) {
                GemmP ge{};
                ge.A = winb + (size_t)c * 32768 * 256; ge.Bt = eT; ge.K = 256; ge.outf = scrf;
                gemm_kernel<4><<<dim3(256, 4), 256, 0, stream>>>(ge);
                expand_ln_kernel<<<dim3(16384), 256, 0, stream>>>(scrf, h, eg, eb, c * 32768, s);
            }
        }
    }
}

// Round 8
// 2446.844 us; speedup vs baseline: 1.0629x; 1.0551x over previous
//
#include <hip/hip_runtime.h>

typedef __bf16 bf16x8 __attribute__((ext_vector_type(8)));
typedef float f32x4 __attribute__((ext_vector_type(4)));
typedef unsigned short u16;
typedef unsigned int u32;

// ---------------- helpers ----------------
__device__ __forceinline__ u16 f2b(float f) {
    union { float f; u32 u; } v; v.f = f;
    u32 r = v.u + 0x7fffu + ((v.u >> 16) & 1u);
    return (u16)(r >> 16);
}
__device__ __forceinline__ float b2f(u16 u) {
    union { u32 u; float f; } v; v.u = ((u32)u) << 16; return v.f;
}
__device__ __forceinline__ void gl_lds16(const u16* g, u16* l) {
    __builtin_amdgcn_global_load_lds(
        (const __attribute__((address_space(1))) void*)g,
        (__attribute__((address_space(3))) void*)l, 16, 0, 0);
}

// ---------------- LN (+shift+window-partition) ----------------
__global__ __launch_bounds__(256) void ln_kernel(
    const float* __restrict__ h, u16* __restrict__ out,
    const float* __restrict__ g, const float* __restrict__ bb,
    int D, int dsh, int shifted, int mode)
{
    const int lane = threadIdx.x & 63;
    const int t = blockIdx.x * 4 + (threadIdx.x >> 6);
    const float4 xv = *(const float4*)(h + (size_t)t * 256 + lane * 4);
    float s = xv.x + xv.y + xv.z + xv.w;
    float s2 = xv.x*xv.x + xv.y*xv.y + xv.z*xv.z + xv.w*xv.w;
    #pragma unroll
    for (int o = 32; o > 0; o >>= 1) { s += __shfl_xor(s, o); s2 += __shfl_xor(s2, o); }
    const float mu = s * 0.00390625f;
    const float var = s2 * 0.00390625f - mu * mu;
    const float rs = 1.0f / sqrtf(var + 1e-5f);
    const int c0 = lane * 4;
    const float4 gv = *(const float4*)(g + c0);
    const float4 bv = *(const float4*)(bb + c0);
    ushort4 o4;
    o4.x = f2b((xv.x - mu) * rs * gv.x + bv.x);
    o4.y = f2b((xv.y - mu) * rs * gv.y + bv.y);
    o4.z = f2b((xv.z - mu) * rs * gv.z + bv.z);
    o4.w = f2b((xv.w - mu) * rs * gv.w + bv.w);
    size_t oidx;
    if (mode == 1) {
        oidx = (size_t)t * 256 + c0;
    } else {
        const int b = t >> (dsh + 12);
        const int rem = t & ((1 << (dsh + 12)) - 1);
        int d = rem >> 12;
        const int l = rem & 4095;
        int hh = l >> 6, ww = l & 63;
        if (shifted) { d = d ? d - 1 : D - 1; hh = (hh - 4) & 63; ww = (ww - 4) & 63; }
        const int widx = (b << (dsh + 5)) + ((d >> 1) << 6) + ((hh >> 3) << 3) + (ww >> 3);
        const int n = ((d & 1) << 6) + ((hh & 7) << 3) + (ww & 7);
        oidx = ((size_t)(widx * 128 + n)) * 256 + c0;
    }
    *(ushort4*)(out + oidx) = o4;
}

// ---------------- fp32 -> bf16 cast ----------------
__global__ __launch_bounds__(256) void cast_kernel(const float* __restrict__ in, u16* __restrict__ out, int n4)
{
    const int i = blockIdx.x * 256 + threadIdx.x;
    if (i >= n4) return;
    const float4 v = ((const float4*)in)[i];
    ushort4 o; o.x = f2b(v.x); o.y = f2b(v.y); o.z = f2b(v.z); o.w = f2b(v.w);
    ((ushort4*)out)[i] = o;
}

// ---------------- weight transpose+cast ----------------
__global__ __launch_bounds__(256) void wt_kernel(const float* __restrict__ src, u16* __restrict__ dst, int K, int N)
{
    const size_t base = (size_t)blockIdx.y * K * N;
    const int idx = blockIdx.x * 256 + threadIdx.x;
    const int k = idx / N, n = idx - k * N;
    dst[base + (size_t)n * K + k] = f2b(src[base + idx]);
}

// ---------------- W1 fragment-major pack ----------------
// dst[((c*8+kt)*4+n)*512 + lane*8 + e] = W1[kt*32 + (lane>>4)*8 + e][c*64 + n*16 + (lane&15)]
__global__ __launch_bounds__(256) void wt1f_kernel(const float* __restrict__ src, u16* __restrict__ dst)
{
    const size_t base = (size_t)blockIdx.y * 262144;
    const int t = blockIdx.x * 256 + threadIdx.x;   // 0..262143
    const int e = t & 7, lane = (t >> 3) & 63, n = (t >> 9) & 3, kt = (t >> 11) & 7, c = t >> 14;
    const int k = kt * 32 + (lane >> 4) * 8 + e;
    const int mid = c * 64 + n * 16 + (lane & 15);
    dst[base + t] = f2b(src[base + (size_t)k * 1024 + mid]);
}

// ---------------- W2 fragment-major pack (with K-permutation m()) ----------------
// dst[((c*2+kt)*16+nt)*512 + lane*8 + e] = W2[c*64 + m(kt,quad,e)][nt*16 + (lane&15)]
__global__ __launch_bounds__(256) void wt2f_kernel(const float* __restrict__ src, u16* __restrict__ dst)
{
    const size_t base = (size_t)blockIdx.y * 262144;
    const int t = blockIdx.x * 256 + threadIdx.x;
    const int e = t & 7, lane = (t >> 3) & 63, nt = (t >> 9) & 15, kt = (t >> 13) & 1, c = t >> 14;
    const int q = lane >> 4;
    const int mid = (2 * kt + (e >> 2)) * 16 + q * 4 + (e & 3);
    const int k = c * 64 + mid;
    const int out = nt * 16 + (lane & 15);
    dst[base + t] = f2b(src[base + (size_t)k * 256 + out]);
}

// ---------------- MFMA bf16 GEMM, 128x128 tile ----------------
struct GemmP {
    const u16* A; const u16* Bt;
    int K;
    const float* bias;
    u16* outb;
    float* outf;
    const float* hin; float* hout;
    int D, shifted, nwsh, row_off;
};

template <int EPI>
__global__ __launch_bounds__(256, 2) void gemm_kernel(GemmP p)
{
    __shared__ __align__(16) char smem[33792];  // 2x(As 8K | Bs 8K); CF 64x132 f32 overlay
    float* CF = (float*)smem;

    const int tid = threadIdx.x;
    const int m0 = blockIdx.x * 128, n0 = blockIdx.y * 128;
    const int K = p.K;
    const int lane = tid & 63;
    const int wv = tid >> 6;
    const int wm = (wv & 1) * 64, wn = (wv >> 1) * 64;
    const int l16 = lane & 15, quad = lane >> 4;

    f32x4 acc[4][4];
    #pragma unroll
    for (int a = 0; a < 4; a++)
        #pragma unroll
        for (int b = 0; b < 4; b++)
            acc[a][b] = f32x4{0.f, 0.f, 0.f, 0.f};

    const int lrow = lane >> 2;
    const int c16s = (lane & 3) ^ (lrow & 3);
    const int rA0 = wv * 16;
    const u16* Ag = p.A + (size_t)(m0 + rA0 + lrow) * K + c16s * 8;
    const u16* Bg = p.Bt + (size_t)(n0 + rA0 + lrow) * K + c16s * 8;
    const size_t j64 = (size_t)64 * K;
    const int fslot = (quad ^ (l16 & 3)) * 8;

    {
        u16* Al = (u16*)smem + rA0 * 32;
        u16* Bl = (u16*)(smem + 8192) + rA0 * 32;
        gl_lds16(Ag, Al);
        gl_lds16(Ag + j64, Al + 64 * 32);
        gl_lds16(Bg, Bl);
        gl_lds16(Bg + j64, Bl + 64 * 32);
    }
    __syncthreads();

    int kb = 0;
    for (int k0 = 0; k0 < K; k0 += 32, kb ^= 1) {
        if (k0 + 32 < K) {
            char* nb = smem + (kb ^ 1) * 16384;
            u16* Al = (u16*)nb + rA0 * 32;
            u16* Bl = (u16*)(nb + 8192) + rA0 * 32;
            gl_lds16(Ag + k0 + 32, Al);
            gl_lds16(Ag + j64 + k0 + 32, Al + 64 * 32);
            gl_lds16(Bg + k0 + 32, Bl);
            gl_lds16(Bg + j64 + k0 + 32, Bl + 64 * 32);
        }
        const u16* As = (const u16*)(smem + kb * 16384);
        const u16* Bs = (const u16*)(smem + kb * 16384 + 8192);
        bf16x8 af[4], bfr[4];
        #pragma unroll
        for (int mt = 0; mt < 4; mt++) af[mt] = *(const bf16x8*)(As + (wm + mt * 16 + l16) * 32 + fslot);
        #pragma unroll
        for (int nt = 0; nt < 4; nt++) bfr[nt] = *(const bf16x8*)(Bs + (wn + nt * 16 + l16) * 32 + fslot);
        #pragma unroll
        for (int mt = 0; mt < 4; mt++)
            #pragma unroll
            for (int nt = 0; nt < 4; nt++)
                acc[mt][nt] = __builtin_amdgcn_mfma_f32_16x16x32_bf16(af[mt], bfr[nt], acc[mt][nt], 0, 0, 0);
        __syncthreads();
    }

    const int crow = tid >> 2;
    const int p4 = (tid & 3) * 4;
    #pragma unroll
    for (int c = 0; c < 2; c++) {
        if (c) __syncthreads();
        if ((wv & 1) == c) {
            #pragma unroll
            for (int mt = 0; mt < 4; mt++)
                #pragma unroll
                for (int nt = 0; nt < 4; nt++)
                    #pragma unroll
                    for (int i = 0; i < 4; i++)
                        CF[(mt * 16 + quad * 4 + i) * 132 + wn + nt * 16 + l16] = acc[mt][nt][i];
        }
        __syncthreads();
        const int rowg = m0 + c * 64 + crow;
        size_t tokbase = 0;
        if constexpr (EPI == 1) {
            const int widx = rowg >> 7, n = rowg & 127;
            const int b = widx >> p.nwsh, rem = widx & ((1 << p.nwsh) - 1);
            int dd = ((rem >> 6) << 1) + (n >> 6);
            int hh = (((rem >> 3) & 7) << 3) + ((n >> 3) & 7);
            int ww = ((rem & 7) << 3) + (n & 7);
            if (p.shifted) { dd = (dd + 1 == p.D) ? 0 : dd + 1; hh = (hh + 4) & 63; ww = (ww + 4) & 63; }
            tokbase = ((size_t)((b * p.D + dd) * 4096 + hh * 64 + ww)) * 256;
        } else if constexpr (EPI == 3) {
            tokbase = (size_t)(p.row_off + rowg) * 256;
        }
        #pragma unroll
        for (int j = 0; j < 8; j++) {
            const int colf = j * 16 + p4;
            const int colg = n0 + colf;
            const float4 t = *(const float4*)(CF + crow * 132 + colf);
            const float4 bi = (EPI <= 3) ? *(const float4*)(p.bias + colg) : float4{0.f,0.f,0.f,0.f};
            if constexpr (EPI == 0) {
                const float sc = (colg < 256) ? 0.125f : 1.0f;
                ushort4 pk;
                pk.x = f2b((t.x + bi.x) * sc);
                pk.y = f2b((t.y + bi.y) * sc);
                pk.z = f2b((t.z + bi.z) * sc);
                pk.w = f2b((t.w + bi.w) * sc);
                *(ushort4*)(p.outb + (size_t)rowg * 768 + colg) = pk;
            } else if constexpr (EPI == 1 || EPI == 3) {
                const float* hi = p.hin + tokbase + colg;
                float* ho = p.hout + tokbase + colg;
                const float4 r = *(const float4*)hi;
                float4 o;
                o.x = r.x + t.x + bi.x;
                o.y = r.y + t.y + bi.y;
                o.z = r.z + t.z + bi.z;
                o.w = r.w + t.w + bi.w;
                *(float4*)ho = o;
            } else if constexpr (EPI == 2) {
                float4 g4;
                g4.x = t.x + bi.x; g4.y = t.y + bi.y; g4.z = t.z + bi.z; g4.w = t.w + bi.w;
                ushort4 pk;
                pk.x = f2b(0.5f * g4.x * (1.0f + erff(g4.x * 0.7071067811865475f)));
                pk.y = f2b(0.5f * g4.y * (1.0f + erff(g4.y * 0.7071067811865475f)));
                pk.z = f2b(0.5f * g4.z * (1.0f + erff(g4.z * 0.7071067811865475f)));
                pk.w = f2b(0.5f * g4.w * (1.0f + erff(g4.w * 0.7071067811865475f)));
                *(ushort4*)(p.outb + (size_t)rowg * 1024 + colg) = pk;
            } else {
                *(float4*)(p.outf + (size_t)rowg * 512 + colg) = t;
            }
        }
    }
}

// ---------------- fused MLP: out = hin + b2 + gelu(A@W1+b1)@W2 ----------------
// v7: wave-pair dimension split to kill the round-6/7 register spill while
// keeping 2x weight reuse. 8 waves = 4 token-groups (tg) x 2 halves (oh).
// Wave (tg,oh): 32 tokens (2 groups of 16), gemm1 mids oh*32..+32, gemm2
// outputs oh*128..+128. Cross-half mids for gemm2 exchanged via a 16KB LDS
// buffer: a thread's 8 gelu outputs ARE its gemm2 kt=oh fragment (m()
// permutation), so exchange = one 16B lane-linear write+read per group.
// Peak regs ~190 (acc2 64, afr 64) -- fits even a 128 arch/128 acc split.
// Mid-chunk barrier = lgkmcnt(0)+s_barrier only (weight prefetch vmcnt stays
// in flight); end-of-chunk __syncthreads drains it.
struct MlpP {
    const u16* A;      // [T][256] bf16 (LN2 output, linear tokens)
    const u16* W1t;    // fragment-major [16 chunks][8 kt][4 n][64 lane][8]
    const u16* W2t;    // fragment-major [16 chunks][2 kt][16 nt][64 lane][8]
    const float* b1;   // [1024]
    const float* b2;   // [256]
    const float* hin;  // residual in fp32
    float* hout;       // fp32 out
};

__global__ __launch_bounds__(512, 1) void mlp_fused_kernel(MlpP p)
{
    __shared__ __align__(16) char smem[147456]; // W1 dbuf 2x32K @0 | W2 dbuf 2x32K @65536 | exch 16K @131072
    float* CF = (float*)smem;                   // 64x260 f32 epilogue overlay (66560B)
    u16* ex = (u16*)(smem + 131072);            // [tg][g][oh][lane*8] pa exchange

    const int tid = threadIdx.x;
    const int lane = tid & 63;
    const int wv = tid >> 6;                    // 0..7
    const int tg = wv >> 1, oh = wv & 1;
    const int l16 = lane & 15, quad = lane >> 4;
    const int tok0 = blockIdx.x * 128;

    // ---- A fragments -> registers (2 token groups of 16) ----
    bf16x8 afr[2][8];
    #pragma unroll
    for (int g = 0; g < 2; g++)
        #pragma unroll
        for (int kt = 0; kt < 8; kt++)
            afr[g][kt] = *(const bf16x8*)(p.A + (size_t)(tok0 + tg * 32 + g * 16 + l16) * 256 + kt * 32 + quad * 8);

    f32x4 acc2[2][8];
    #pragma unroll
    for (int g = 0; g < 2; g++)
        #pragma unroll
        for (int nt = 0; nt < 8; nt++)
            acc2[g][nt] = f32x4{0.f, 0.f, 0.f, 0.f};

    // ---- fragment-major staging: wave wv stages fragments wv*4..wv*4+3 ----
    auto stage = [&](int c) {
        const u16* w1g = p.W1t + (size_t)c * 16384;
        const u16* w2g = p.W2t + (size_t)c * 16384;
        u16* w1b = (u16*)(smem + (c & 1) * 32768);
        u16* w2b = (u16*)(smem + 65536 + (c & 1) * 32768);
        #pragma unroll
        for (int f = 0; f < 4; f++) {
            const int fr = wv * 4 + f;
            gl_lds16(w1g + fr * 512 + lane * 8, w1b + fr * 512);
            gl_lds16(w2g + fr * 512 + lane * 8, w2b + fr * 512);
        }
    };

    stage(0);
    __syncthreads();

    for (int c = 0; c < 16; c++) {
        if (c + 1 < 16) stage(c + 1);   // prefetch into alternate buffer (vmcnt, flies past mid barrier)

        // ---- gemm1 (swapped): acc1[g][n] = D[mid oh*32+n*16+..][token] ----
        const u16* W1c = (const u16*)(smem + (c & 1) * 32768);
        f32x4 acc1[2][2];
        #pragma unroll
        for (int g = 0; g < 2; g++)
            #pragma unroll
            for (int n = 0; n < 2; n++)
                acc1[g][n] = f32x4{0.f, 0.f, 0.f, 0.f};
        #pragma unroll
        for (int kt = 0; kt < 8; kt++) {
            bf16x8 w1f[2];
            #pragma unroll
            for (int n = 0; n < 2; n++)
                w1f[n] = *(const bf16x8*)(W1c + (kt * 4 + oh * 2 + n) * 512 + lane * 8);
            #pragma unroll
            for (int g = 0; g < 2; g++)
                #pragma unroll
                for (int n = 0; n < 2; n++)
                    acc1[g][n] = __builtin_amdgcn_mfma_f32_16x16x32_bf16(w1f[n], afr[g][kt], acc1[g][n], 0, 0, 0);
        }

        // ---- bias + gelu (exp form) -> pa[g] (own kt=oh fragment) ----
        bf16x8 pa[2];
        #pragma unroll
        for (int n = 0; n < 2; n++) {
            const float4 b1q = *(const float4*)(p.b1 + c * 64 + oh * 32 + n * 16 + quad * 4);
            #pragma unroll
            for (int i = 0; i < 4; i++) {
                const float b1i = (i == 0) ? b1q.x : (i == 1) ? b1q.y : (i == 2) ? b1q.z : b1q.w;
                #pragma unroll
                for (int g = 0; g < 2; g++) {
                    const float x = acc1[g][n][i] + b1i;
                    const float u = x * (1.0f + 0.044715f * x * x);
                    const float em = __expf(-1.5957691216f * u);
                    const float gv = x * __builtin_amdgcn_rcpf(1.0f + em);
                    pa[g][n * 4 + i] = (__bf16)gv;
                }
            }
        }

        // ---- exchange own-half fragments with partner wave ----
        #pragma unroll
        for (int g = 0; g < 2; g++)
            *(bf16x8*)(ex + ((tg * 2 + g) * 2 + oh) * 512 + lane * 8) = pa[g];
        asm volatile("s_waitcnt lgkmcnt(0)\ns_barrier" ::: "memory");

        // ---- gemm2: acc2[g][nt] += P @ W2c (outputs oh*128..+128) ----
        const u16* W2c = (const u16*)(smem + 65536 + (c & 1) * 32768);
        #pragma unroll
        for (int kt = 0; kt < 2; kt++) {
            bf16x8 a2[2];
            if (kt == oh) {
                a2[0] = pa[0]; a2[1] = pa[1];
            } else {
                #pragma unroll
                for (int g = 0; g < 2; g++)
                    a2[g] = *(const bf16x8*)(ex + ((tg * 2 + g) * 2 + (1 - oh)) * 512 + lane * 8);
            }
            #pragma unroll
            for (int nt = 0; nt < 8; nt++) {
                const bf16x8 w2f = *(const bf16x8*)(W2c + (kt * 16 + oh * 8 + nt) * 512 + lane * 8);
                #pragma unroll
                for (int g = 0; g < 2; g++)
                    acc2[g][nt] = __builtin_amdgcn_mfma_f32_16x16x32_bf16(a2[g], w2f, acc2[g][nt], 0, 0, 0);
            }
        }
        __syncthreads();   // exch + buf[c&1] reads done; stage(c+1) drained (vmcnt0)
    }

    float b2v[8];
    #pragma unroll
    for (int nt = 0; nt < 8; nt++) b2v[nt] = p.b2[oh * 128 + nt * 16 + l16];

    // ---- transposed epilogue: 2 chunks of 64 rows through CF (stride 260) ----
    // acc2[g][nt][i]: token = tg*32 + g*16 + quad*4 + i, out = oh*128 + nt*16 + l16.
    #pragma unroll
    for (int cc = 0; cc < 2; cc++) {
        __syncthreads();
        if ((wv >> 2) == cc) {
            const int rb = (tg & 1) * 32;
            #pragma unroll
            for (int g = 0; g < 2; g++)
                #pragma unroll
                for (int nt = 0; nt < 8; nt++)
                    #pragma unroll
                    for (int i = 0; i < 4; i++)
                        CF[(rb + g * 16 + quad * 4 + i) * 260 + oh * 128 + nt * 16 + l16] = acc2[g][nt][i] + b2v[nt];
        }
        __syncthreads();
        #pragma unroll
        for (int jj = 0; jj < 8; jj++) {
            const int idx = jj * 512 + tid;           // 0..4095
            const int row = idx >> 6, c4 = (idx & 63) << 2;
            const size_t g = (size_t)(tok0 + cc * 64 + row) * 256 + c4;
            const float4 t = *(const float4*)(CF + row * 260 + c4);
            const float4 r = *(const float4*)(p.hin + g);
            float4 o;
            o.x = t.x + r.x; o.y = t.y + r.y; o.z = t.z + r.z; o.w = t.w + r.w;
            *(float4*)(p.hout + g) = o;
        }
    }
}

// ---------------- MFMA attention: one block per (window, head) ----------------
__global__ __launch_bounds__(256, 2) void attn_mfma_kernel(
    const u16* __restrict__ qkv, u16* __restrict__ att,
    const float* __restrict__ rpbp, int D, int shifted, int w0g, int nwsh)
{
    __shared__ __align__(16) char smem[57856];
    u16* Qs = (u16*)smem;
    u16* Ks = (u16*)(smem + 18432);
    u16* Ps = (u16*)smem;
    u16* Vt = (u16*)(smem + 36864);
    float* rb = (float*)(smem + 54272);
    int* lbl = (int*)(smem + 56972);

    const int wloc = blockIdx.x;
    const int head = blockIdx.y;
    const int tid = threadIdx.x;
    const u16* base = qkv + (size_t)wloc * 98304;

    #pragma unroll
    for (int it = 0; it < 4; it++) {
        const int id = it * 256 + tid;
        const int row = id >> 3, oct = id & 7;
        const size_t ro = (size_t)row * 768 + head * 64 + oct * 8;
        *(uint4*)(Qs + row * 72 + oct * 8) = *(const uint4*)(base + ro);
        *(uint4*)(Ks + row * 72 + oct * 8) = *(const uint4*)(base + ro + 256);
        uint4 vv = *(const uint4*)(base + ro + 512);
        const u16* vp = (const u16*)&vv;
        #pragma unroll
        for (int q = 0; q < 8; q++) Vt[(oct * 8 + q) * 136 + row] = vp[q];
    }
    for (int j = tid; j < 675; j += 256) rb[j] = rpbp[j * 4 + head];
    if (tid < 128) {
        int lv = 0;
        if (shifted) {
            const int widx = w0g + wloc;
            const int rem = widx & ((1 << nwsh) - 1);
            const int d0 = rem >> 6, h0 = (rem >> 3) & 7, w0 = rem & 7;
            const int wd = tid >> 6, wh = (tid >> 3) & 7, ww = tid & 7;
            const int rd = (d0 < (D >> 1) - 1) ? 0 : (1 + wd);
            const int rh = (h0 < 7) ? 0 : (1 + (wh >= 4));
            const int rw = (w0 < 7) ? 0 : (1 + (ww >= 4));
            lv = rd * 9 + rh * 3 + rw;
        }
        lbl[tid] = lv;
    }
    __syncthreads();

    const int wq = tid >> 6;
    const int lane = tid & 63;
    const int l16 = lane & 15, quad = lane >> 4;
    const int myrow0 = wq * 32;

    f32x4 sc[2][8];
    #pragma unroll
    for (int mt = 0; mt < 2; mt++)
        #pragma unroll
        for (int nt = 0; nt < 8; nt++)
            sc[mt][nt] = f32x4{0.f, 0.f, 0.f, 0.f};
    #pragma unroll
    for (int kt = 0; kt < 2; kt++) {
        bf16x8 aq[2];
        #pragma unroll
        for (int mt = 0; mt < 2; mt++)
            aq[mt] = *(const bf16x8*)(Qs + (myrow0 + mt * 16 + l16) * 72 + kt * 32 + quad * 8);
        bf16x8 bk[8];
        #pragma unroll
        for (int nt = 0; nt < 8; nt++)
            bk[nt] = *(const bf16x8*)(Ks + (nt * 16 + l16) * 72 + kt * 32 + quad * 8);
        #pragma unroll
        for (int mt = 0; mt < 2; mt++)
            #pragma unroll
            for (int nt = 0; nt < 8; nt++)
                sc[mt][nt] = __builtin_amdgcn_mfma_f32_16x16x32_bf16(aq[mt], bk[nt], sc[mt][nt], 0, 0, 0);
    }

    float linv[2][4];
    #pragma unroll
    for (int mt = 0; mt < 2; mt++) {
        #pragma unroll
        for (int i = 0; i < 4; i++) {
            const int row = myrow0 + mt * 16 + quad * 4 + i;
            const int rbase = ((row >> 6) + 1) * 225 + (((row >> 3) & 7) + 7) * 15 + ((row & 7) + 7);
            const int lq = lbl[row];
            float mx = -1e30f;
            float sv[8];
            #pragma unroll
            for (int nt = 0; nt < 8; nt++) {
                const int col = nt * 16 + l16;
                float v = sc[mt][nt][i] + rb[rbase - (col >> 6) * 225 - ((col >> 3) & 7) * 15 - (col & 7)];
                if (shifted && lq != lbl[col]) v -= 100.0f;
                sv[nt] = v;
                mx = fmaxf(mx, v);
            }
            #pragma unroll
            for (int o = 1; o < 16; o <<= 1) mx = fmaxf(mx, __shfl_xor(mx, o));
            float l = 0.0f;
            #pragma unroll
            for (int nt = 0; nt < 8; nt++) {
                const float pp = __expf(sv[nt] - mx);
                sc[mt][nt][i] = pp;
                l += pp;
            }
            #pragma unroll
            for (int o = 1; o < 16; o <<= 1) l += __shfl_xor(l, o);
            linv[mt][i] = 1.0f / l;
        }
    }

    __syncthreads();
    #pragma unroll
    for (int mt = 0; mt < 2; mt++)
        #pragma unroll
        for (int nt = 0; nt < 8; nt++)
            #pragma unroll
            for (int i = 0; i < 4; i++)
                Ps[(myrow0 + mt * 16 + quad * 4 + i) * 136 + nt * 16 + l16] = f2b(sc[mt][nt][i]);

    f32x4 oc[2][4];
    #pragma unroll
    for (int mt = 0; mt < 2; mt++)
        #pragma unroll
        for (int nt = 0; nt < 4; nt++)
            oc[mt][nt] = f32x4{0.f, 0.f, 0.f, 0.f};
    #pragma unroll
    for (int kt = 0; kt < 4; kt++) {
        bf16x8 ap[2];
        #pragma unroll
        for (int mt = 0; mt < 2; mt++)
            ap[mt] = *(const bf16x8*)(Ps + (myrow0 + mt * 16 + l16) * 136 + kt * 32 + quad * 8);
        bf16x8 bv[4];
        #pragma unroll
        for (int nt = 0; nt < 4; nt++)
            bv[nt] = *(const bf16x8*)(Vt + (nt * 16 + l16) * 136 + kt * 32 + quad * 8);
        #pragma unroll
        for (int mt = 0; mt < 2; mt++)
            #pragma unroll
            for (int nt = 0; nt < 4; nt++)
                oc[mt][nt] = __builtin_amdgcn_mfma_f32_16x16x32_bf16(ap[mt], bv[nt], oc[mt][nt], 0, 0, 0);
    }

    #pragma unroll
    for (int mt = 0; mt < 2; mt++)
        #pragma unroll
        for (int nt = 0; nt < 4; nt++)
            #pragma unroll
            for (int i = 0; i < 4; i++) {
                const int row = myrow0 + mt * 16 + quad * 4 + i;
                const int col = nt * 16 + l16;
                att[(size_t)(wloc * 128 + row) * 256 + head * 64 + col] = f2b(oc[mt][nt][i] * linv[mt][i]);
            }
}

// ---------------- patch-expand LN + reorder ----------------
__global__ __launch_bounds__(256) void expand_ln_kernel(
    const float* __restrict__ sc, float* __restrict__ hout,
    const float* __restrict__ g, const float* __restrict__ bb,
    int it0, int typ)
{
    const int lane = threadIdx.x & 63;
    const int ot = blockIdx.x * 4 + (threadIdx.x >> 6);
    const int itl = ot >> 1, e = ot & 1;
    const float4 xv = *(const float4*)(sc + (size_t)itl * 512 + e * 256 + lane * 4);
    float s = xv.x + xv.y + xv.z + xv.w;
    float s2 = xv.x*xv.x + xv.y*xv.y + xv.z*xv.z + xv.w*xv.w;
    #pragma unroll
    for (int o = 32; o > 0; o >>= 1) { s += __shfl_xor(s, o); s2 += __shfl_xor(s2, o); }
    const float mu = s * 0.00390625f;
    const float var = s2 * 0.00390625f - mu * mu;
    const float rs = 1.0f / sqrtf(var + 1e-5f);
    const int c0 = lane * 4;
    const float4 gv = *(const float4*)(g + c0);
    const float4 bv = *(const float4*)(bb + c0);
    float4 y;
    y.x = (xv.x - mu) * rs * gv.x + bv.x;
    y.y = (xv.y - mu) * rs * gv.y + bv.y;
    y.z = (xv.z - mu) * rs * gv.z + bv.z;
    y.w = (xv.w - mu) * rs * gv.w + bv.w;
    const int it = it0 + itl;
    size_t otg;
    if (typ == 0) {
        const int b = it >> 14, rr = it & 16383;
        const int t = rr >> 13, v = (rr >> 12) & 1, l = rr & 4095;
        otg = (size_t)(((b * 2 + t) * 4 + v * 2 + e) * 4096 + l);
    } else {
        const int b = it >> 15, rr = it & 32767;
        const int t = rr >> 14, v2 = (rr >> 12) & 3, l = rr & 4095;
        otg = (size_t)(((b * 4 + t * 2 + e) * 4 + v2) * 4096 + l);
    }
    *(float4*)(hout + otg * 256 + c0) = y;
}

// ---------------- host ----------------
extern "C" void kernel_launch(void* const* d_in, const int* in_sizes, int n_in,
                              void* d_out, int out_size, void* d_ws, size_t ws_size,
                              hipStream_t stream)
{
    const float* x      = (const float*)d_in[0];
    const float* n1w    = (const float*)d_in[1];
    const float* n1b    = (const float*)d_in[2];
    const float* qkv_w  = (const float*)d_in[3];
    const float* qkv_b  = (const float*)d_in[4];
    const float* rpb    = (const float*)d_in[5];
    const float* proj_w = (const float*)d_in[6];
    const float* proj_b = (const float*)d_in[7];
    const float* n2w    = (const float*)d_in[8];
    const float* n2b    = (const float*)d_in[9];
    const float* mlp1_w = (const float*)d_in[10];
    const float* mlp1_b = (const float*)d_in[11];
    const float* mlp2_w = (const float*)d_in[12];
    const float* mlp2_b = (const float*)d_in[13];
    const float* expv_w = (const float*)d_in[14];
    const float* expv_nw= (const float*)d_in[15];
    const float* expv_nb= (const float*)d_in[16];
    const float* expt_w = (const float*)d_in[17];
    const float* expt_nw= (const float*)d_in[18];
    const float* expt_nb= (const float*)d_in[19];
    (void)in_sizes; (void)n_in; (void)out_size;

    if (ws_size < 352321536ULL) return;

    char* ws = (char*)d_ws;
    float* h    = (float*)ws;
    u16*  winb  = (u16*)(ws + 134217728LL);
    u16*  att   = (u16*)(ws + 134217728LL + 67108864LL);
    char* scr   = ws + 134217728LL + 2LL * 67108864LL;
    u16*  scrb  = (u16*)scr;
    float* scrf = (float*)scr;
    u16* qkvT   = (u16*)(ws + 134217728LL + 3LL * 67108864LL);
    u16* projT  = qkvT + 6 * 768 * 256;
    u16* mlp1T  = projT + 6 * 256 * 256;
    u16* mlp2T  = mlp1T + 6 * 1024 * 256;
    u16* expvT  = mlp2T + 6 * 256 * 1024;
    u16* exptT  = expvT + 512 * 256;

    wt_kernel<<<dim3(768, 6), 256, 0, stream>>>(qkv_w, qkvT, 256, 768);
    wt_kernel<<<dim3(256, 6), 256, 0, stream>>>(proj_w, projT, 256, 256);
    wt1f_kernel<<<dim3(1024, 6), 256, 0, stream>>>(mlp1_w, mlp1T);
    wt2f_kernel<<<dim3(1024, 6), 256, 0, stream>>>(mlp2_w, mlp2T);
    wt_kernel<<<dim3(512, 1), 256, 0, stream>>>(expv_w, expvT, 256, 512);
    wt_kernel<<<dim3(512, 1), 256, 0, stream>>>(expt_w, exptT, 256, 512);
    hipMemcpyAsync(h, x, 33554432ULL, hipMemcpyDeviceToDevice, stream);

    for (int s = 0; s < 3; s++) {
        const int D = 4 << s;
        const int dsh = 2 + s;
        const int nwsh = dsh + 5;
        const int tokens = 2 * D * 4096;
        const int nch = tokens / 32768;
        for (int j = 0; j < 2; j++) {
            const int i = 2 * s + j;
            ln_kernel<<<dim3(tokens / 4), 256, 0, stream>>>(h, winb, n1w + i * 256, n1b + i * 256, D, dsh, j, 0);
            for (int c = 0; c < nch; c++) {
                GemmP gq{};
                gq.A = winb + (size_t)c * 32768 * 256;
                gq.Bt = qkvT + (size_t)i * 768 * 256;
                gq.K = 256; gq.bias = qkv_b + i * 768; gq.outb = scrb;
                gemm_kernel<0><<<dim3(256, 6), 256, 0, stream>>>(gq);
                attn_mfma_kernel<<<dim3(256, 4), 256, 0, stream>>>(scrb, att + (size_t)c * 32768 * 256,
                                                                   rpb + i * 675 * 4, D, j, c * 256, nwsh);
            }
            GemmP gp{};
            gp.A = att; gp.Bt = projT + (size_t)i * 256 * 256; gp.K = 256;
            gp.bias = proj_b + i * 256; gp.hin = h; gp.hout = h;
            gp.D = D; gp.shifted = j; gp.nwsh = nwsh;
            gemm_kernel<1><<<dim3(tokens / 128, 2), 256, 0, stream>>>(gp);
            ln_kernel<<<dim3(tokens / 4), 256, 0, stream>>>(h, winb, n2w + i * 256, n2b + i * 256, D, dsh, 0, 1);
            MlpP mp{};
            mp.A = winb;
            mp.W1t = mlp1T + (size_t)i * 262144;
            mp.W2t = mlp2T + (size_t)i * 262144;
            mp.b1 = mlp1_b + i * 1024;
            mp.b2 = mlp2_b + i * 256;
            mp.hin = h;
            mp.hout = (s == 2 && j == 1) ? (float*)d_out : h;
            mlp_fused_kernel<<<dim3(tokens / 128), 512, 0, stream>>>(mp);
        }
        if (s < 2) {
            const int ntok = tokens;
            cast_kernel<<<dim3(ntok * 64 / 256), 256, 0, stream>>>(h, winb, ntok * 64);
            const u16* eT = (s == 0) ? expvT : exptT;
            const float* eg = (s == 0) ? expv_nw : expt_nw;
            const float* eb = (s == 0) ? expv_nb : expt_nb;
            for (int c = 0; c < ntok / 32768; c++) {
                GemmP ge{};
                ge.A = winb + (size_t)c * 32768 * 256; ge.Bt = eT; ge.K = 256; ge.outf = scrf;
                gemm_kernel<4><<<dim3(256, 4), 256, 0, stream>>>(ge);
                expand_ln_kernel<<<dim3(16384), 256, 0, stream>>>(scrf, h, eg, eb, c * 32768, s);
            }
        }
    }
}

// Round 9
// 2367.966 us; speedup vs baseline: 1.0983x; 1.0333x over previous
//
#include <hip/hip_runtime.h>

typedef __bf16 bf16x8 __attribute__((ext_vector_type(8)));
typedef float f32x4 __attribute__((ext_vector_type(4)));
typedef unsigned short u16;
typedef unsigned int u32;

// ---------------- helpers ----------------
__device__ __forceinline__ u16 f2b(float f) {
    union { float f; u32 u; } v; v.f = f;
    u32 r = v.u + 0x7fffu + ((v.u >> 16) & 1u);
    return (u16)(r >> 16);
}
__device__ __forceinline__ float b2f(u16 u) {
    union { u32 u; float f; } v; v.u = ((u32)u) << 16; return v.f;
}
__device__ __forceinline__ void gl_lds16(const u16* g, u16* l) {
    __builtin_amdgcn_global_load_lds(
        (const __attribute__((address_space(1))) void*)g,
        (__attribute__((address_space(3))) void*)l, 16, 0, 0);
}

// ---------------- LN (+shift+window-partition) ----------------
__global__ __launch_bounds__(256) void ln_kernel(
    const float* __restrict__ h, u16* __restrict__ out,
    const float* __restrict__ g, const float* __restrict__ bb,
    int D, int dsh, int shifted, int mode)
{
    const int lane = threadIdx.x & 63;
    const int t = blockIdx.x * 4 + (threadIdx.x >> 6);
    const float4 xv = *(const float4*)(h + (size_t)t * 256 + lane * 4);
    float s = xv.x + xv.y + xv.z + xv.w;
    float s2 = xv.x*xv.x + xv.y*xv.y + xv.z*xv.z + xv.w*xv.w;
    #pragma unroll
    for (int o = 32; o > 0; o >>= 1) { s += __shfl_xor(s, o); s2 += __shfl_xor(s2, o); }
    const float mu = s * 0.00390625f;
    const float var = s2 * 0.00390625f - mu * mu;
    const float rs = 1.0f / sqrtf(var + 1e-5f);
    const int c0 = lane * 4;
    const float4 gv = *(const float4*)(g + c0);
    const float4 bv = *(const float4*)(bb + c0);
    ushort4 o4;
    o4.x = f2b((xv.x - mu) * rs * gv.x + bv.x);
    o4.y = f2b((xv.y - mu) * rs * gv.y + bv.y);
    o4.z = f2b((xv.z - mu) * rs * gv.z + bv.z);
    o4.w = f2b((xv.w - mu) * rs * gv.w + bv.w);
    size_t oidx;
    if (mode == 1) {
        oidx = (size_t)t * 256 + c0;
    } else {
        const int b = t >> (dsh + 12);
        const int rem = t & ((1 << (dsh + 12)) - 1);
        int d = rem >> 12;
        const int l = rem & 4095;
        int hh = l >> 6, ww = l & 63;
        if (shifted) { d = d ? d - 1 : D - 1; hh = (hh - 4) & 63; ww = (ww - 4) & 63; }
        const int widx = (b << (dsh + 5)) + ((d >> 1) << 6) + ((hh >> 3) << 3) + (ww >> 3);
        const int n = ((d & 1) << 6) + ((hh & 7) << 3) + (ww & 7);
        oidx = ((size_t)(widx * 128 + n)) * 256 + c0;
    }
    *(ushort4*)(out + oidx) = o4;
}

// ---------------- fp32 -> bf16 cast ----------------
__global__ __launch_bounds__(256) void cast_kernel(const float* __restrict__ in, u16* __restrict__ out, int n4)
{
    const int i = blockIdx.x * 256 + threadIdx.x;
    if (i >= n4) return;
    const float4 v = ((const float4*)in)[i];
    ushort4 o; o.x = f2b(v.x); o.y = f2b(v.y); o.z = f2b(v.z); o.w = f2b(v.w);
    ((ushort4*)out)[i] = o;
}

// ---------------- weight transpose+cast ----------------
__global__ __launch_bounds__(256) void wt_kernel(const float* __restrict__ src, u16* __restrict__ dst, int K, int N)
{
    const size_t base = (size_t)blockIdx.y * K * N;
    const int idx = blockIdx.x * 256 + threadIdx.x;
    const int k = idx / N, n = idx - k * N;
    dst[base + (size_t)n * K + k] = f2b(src[base + idx]);
}

// ---------------- W1 fragment-major pack (32-mid chunks) ----------------
// dst[((c32*8+kt)*2+n2)*512 + lane*8 + e] = W1[kt*32 + (lane>>4)*8 + e][c32*32 + n2*16 + (lane&15)]
__global__ __launch_bounds__(256) void wt1f_kernel(const float* __restrict__ src, u16* __restrict__ dst)
{
    const size_t base = (size_t)blockIdx.y * 262144;
    const int t = blockIdx.x * 256 + threadIdx.x;   // 0..262143
    const int e = t & 7, lane = (t >> 3) & 63, n2 = (t >> 9) & 1, kt = (t >> 10) & 7, c = t >> 13;
    const int k = kt * 32 + (lane >> 4) * 8 + e;
    const int mid = c * 32 + n2 * 16 + (lane & 15);
    dst[base + t] = f2b(src[base + (size_t)k * 1024 + mid]);
}

// ---------------- W2 fragment-major pack (32-mid chunks, K-perm m32()) ----------------
// dst[(c32*16+nt)*512 + lane*8 + e] = W2[c32*32 + m32(q,e)][nt*16 + (lane&15)]
// m32(q,e) = (e>>2)*16 + q*4 + (e&3) -- mid order a thread holds after swapped
// gemm1 with 2 mid-tiles (pa[n2*4+i], mid = n2*16 + q*4 + i).
__global__ __launch_bounds__(256) void wt2f_kernel(const float* __restrict__ src, u16* __restrict__ dst)
{
    const size_t base = (size_t)blockIdx.y * 262144;
    const int t = blockIdx.x * 256 + threadIdx.x;
    const int e = t & 7, lane = (t >> 3) & 63, nt = (t >> 9) & 15, c = t >> 13;
    const int q = lane >> 4;
    const int mid = (e >> 2) * 16 + q * 4 + (e & 3);
    const int k = c * 32 + mid;
    const int out = nt * 16 + (lane & 15);
    dst[base + t] = f2b(src[base + (size_t)k * 256 + out]);
}

// ---------------- MFMA bf16 GEMM, 128x128 tile ----------------
struct GemmP {
    const u16* A; const u16* Bt;
    int K;
    const float* bias;
    u16* outb;
    float* outf;
    const float* hin; float* hout;
    int D, shifted, nwsh, row_off;
};

template <int EPI>
__global__ __launch_bounds__(256, 2) void gemm_kernel(GemmP p)
{
    __shared__ __align__(16) char smem[33792];  // 2x(As 8K | Bs 8K); CF 64x132 f32 overlay
    float* CF = (float*)smem;

    const int tid = threadIdx.x;
    const int m0 = blockIdx.x * 128, n0 = blockIdx.y * 128;
    const int K = p.K;
    const int lane = tid & 63;
    const int wv = tid >> 6;
    const int wm = (wv & 1) * 64, wn = (wv >> 1) * 64;
    const int l16 = lane & 15, quad = lane >> 4;

    f32x4 acc[4][4];
    #pragma unroll
    for (int a = 0; a < 4; a++)
        #pragma unroll
        for (int b = 0; b < 4; b++)
            acc[a][b] = f32x4{0.f, 0.f, 0.f, 0.f};

    const int lrow = lane >> 2;
    const int c16s = (lane & 3) ^ (lrow & 3);
    const int rA0 = wv * 16;
    const u16* Ag = p.A + (size_t)(m0 + rA0 + lrow) * K + c16s * 8;
    const u16* Bg = p.Bt + (size_t)(n0 + rA0 + lrow) * K + c16s * 8;
    const size_t j64 = (size_t)64 * K;
    const int fslot = (quad ^ (l16 & 3)) * 8;

    {
        u16* Al = (u16*)smem + rA0 * 32;
        u16* Bl = (u16*)(smem + 8192) + rA0 * 32;
        gl_lds16(Ag, Al);
        gl_lds16(Ag + j64, Al + 64 * 32);
        gl_lds16(Bg, Bl);
        gl_lds16(Bg + j64, Bl + 64 * 32);
    }
    __syncthreads();

    int kb = 0;
    for (int k0 = 0; k0 < K; k0 += 32, kb ^= 1) {
        if (k0 + 32 < K) {
            char* nb = smem + (kb ^ 1) * 16384;
            u16* Al = (u16*)nb + rA0 * 32;
            u16* Bl = (u16*)(nb + 8192) + rA0 * 32;
            gl_lds16(Ag + k0 + 32, Al);
            gl_lds16(Ag + j64 + k0 + 32, Al + 64 * 32);
            gl_lds16(Bg + k0 + 32, Bl);
            gl_lds16(Bg + j64 + k0 + 32, Bl + 64 * 32);
        }
        const u16* As = (const u16*)(smem + kb * 16384);
        const u16* Bs = (const u16*)(smem + kb * 16384 + 8192);
        bf16x8 af[4], bfr[4];
        #pragma unroll
        for (int mt = 0; mt < 4; mt++) af[mt] = *(const bf16x8*)(As + (wm + mt * 16 + l16) * 32 + fslot);
        #pragma unroll
        for (int nt = 0; nt < 4; nt++) bfr[nt] = *(const bf16x8*)(Bs + (wn + nt * 16 + l16) * 32 + fslot);
        #pragma unroll
        for (int mt = 0; mt < 4; mt++)
            #pragma unroll
            for (int nt = 0; nt < 4; nt++)
                acc[mt][nt] = __builtin_amdgcn_mfma_f32_16x16x32_bf16(af[mt], bfr[nt], acc[mt][nt], 0, 0, 0);
        __syncthreads();
    }

    const int crow = tid >> 2;
    const int p4 = (tid & 3) * 4;
    #pragma unroll
    for (int c = 0; c < 2; c++) {
        if (c) __syncthreads();
        if ((wv & 1) == c) {
            #pragma unroll
            for (int mt = 0; mt < 4; mt++)
                #pragma unroll
                for (int nt = 0; nt < 4; nt++)
                    #pragma unroll
                    for (int i = 0; i < 4; i++)
                        CF[(mt * 16 + quad * 4 + i) * 132 + wn + nt * 16 + l16] = acc[mt][nt][i];
        }
        __syncthreads();
        const int rowg = m0 + c * 64 + crow;
        size_t tokbase = 0;
        if constexpr (EPI == 1) {
            const int widx = rowg >> 7, n = rowg & 127;
            const int b = widx >> p.nwsh, rem = widx & ((1 << p.nwsh) - 1);
            int dd = ((rem >> 6) << 1) + (n >> 6);
            int hh = (((rem >> 3) & 7) << 3) + ((n >> 3) & 7);
            int ww = ((rem & 7) << 3) + (n & 7);
            if (p.shifted) { dd = (dd + 1 == p.D) ? 0 : dd + 1; hh = (hh + 4) & 63; ww = (ww + 4) & 63; }
            tokbase = ((size_t)((b * p.D + dd) * 4096 + hh * 64 + ww)) * 256;
        } else if constexpr (EPI == 3) {
            tokbase = (size_t)(p.row_off + rowg) * 256;
        }
        #pragma unroll
        for (int j = 0; j < 8; j++) {
            const int colf = j * 16 + p4;
            const int colg = n0 + colf;
            const float4 t = *(const float4*)(CF + crow * 132 + colf);
            const float4 bi = (EPI <= 3) ? *(const float4*)(p.bias + colg) : float4{0.f,0.f,0.f,0.f};
            if constexpr (EPI == 0) {
                const float sc = (colg < 256) ? 0.125f : 1.0f;
                ushort4 pk;
                pk.x = f2b((t.x + bi.x) * sc);
                pk.y = f2b((t.y + bi.y) * sc);
                pk.z = f2b((t.z + bi.z) * sc);
                pk.w = f2b((t.w + bi.w) * sc);
                *(ushort4*)(p.outb + (size_t)rowg * 768 + colg) = pk;
            } else if constexpr (EPI == 1 || EPI == 3) {
                const float* hi = p.hin + tokbase + colg;
                float* ho = p.hout + tokbase + colg;
                const float4 r = *(const float4*)hi;
                float4 o;
                o.x = r.x + t.x + bi.x;
                o.y = r.y + t.y + bi.y;
                o.z = r.z + t.z + bi.z;
                o.w = r.w + t.w + bi.w;
                *(float4*)ho = o;
            } else if constexpr (EPI == 2) {
                float4 g4;
                g4.x = t.x + bi.x; g4.y = t.y + bi.y; g4.z = t.z + bi.z; g4.w = t.w + bi.w;
                ushort4 pk;
                pk.x = f2b(0.5f * g4.x * (1.0f + erff(g4.x * 0.7071067811865475f)));
                pk.y = f2b(0.5f * g4.y * (1.0f + erff(g4.y * 0.7071067811865475f)));
                pk.z = f2b(0.5f * g4.z * (1.0f + erff(g4.z * 0.7071067811865475f)));
                pk.w = f2b(0.5f * g4.w * (1.0f + erff(g4.w * 0.7071067811865475f)));
                *(ushort4*)(p.outb + (size_t)rowg * 1024 + colg) = pk;
            } else {
                *(float4*)(p.outf + (size_t)rowg * 512 + colg) = t;
            }
        }
    }
}

// ---------------- fused MLP: out = hin + b2 + gelu(A@W1+b1)@W2 ----------------
// v8: occupancy fix. Rounds 3-8 all landed 250-270us regardless of inner
// structure -> latency-bound by the chunk-serial barrier lockstep at
// 1 block/CU (Occ 22%, all pipes idle). Fix: LDS 147K -> 72K so TWO blocks
// co-reside per CU (independent block fills barrier/latency stalls).
// Chunk = 32 mids (32 chunks): W1c 16K + W2c 16K, double-buffered = 64K;
// CF epilogue (66.5K) overlays within the 72K. Dataflow = proven r5 form
// (16 tokens/wave, no oh-split, 1 barrier/chunk); acc1 shrinks to [2], so
// peak regs ~115 fits the 128 cap that __launch_bounds__(512,4) declares
// (4 waves/EU = 2 blocks/CU).
struct MlpP {
    const u16* A;      // [T][256] bf16 (LN2 output, linear tokens)
    const u16* W1t;    // fragment-major [32 c][8 kt][2 n2][64 lane][8]
    const u16* W2t;    // fragment-major [32 c][16 nt][64 lane][8]
    const float* b1;   // [1024]
    const float* b2;   // [256]
    const float* hin;  // residual in fp32
    float* hout;       // fp32 out
};

__global__ __launch_bounds__(512, 4) void mlp_fused_kernel(MlpP p)
{
    __shared__ __align__(16) char smem[73728]; // W1 dbuf 2x16K @0 | W2 dbuf 2x16K @32768 | CF overlay
    float* CF = (float*)smem;                  // 64x260 f32 epilogue overlay (66560B)

    const int tid = threadIdx.x;
    const int lane = tid & 63;
    const int wv = tid >> 6;                   // 0..7
    const int l16 = lane & 15, quad = lane >> 4;
    const int tok0 = blockIdx.x * 128;
    const int wtok = wv * 16;                  // wave's 16 tokens

    // ---- A fragments -> registers (B-operand: col=token=l16) ----
    bf16x8 afr[8];
    #pragma unroll
    for (int kt = 0; kt < 8; kt++)
        afr[kt] = *(const bf16x8*)(p.A + (size_t)(tok0 + wtok + l16) * 256 + kt * 32 + quad * 8);

    f32x4 acc2[16];
    #pragma unroll
    for (int nt = 0; nt < 16; nt++) acc2[nt] = f32x4{0.f, 0.f, 0.f, 0.f};

    // ---- staging: 16 W1 + 16 W2 fragments/chunk; wave wv stages 2 of each ----
    auto stage = [&](int c) {
        const u16* w1g = p.W1t + (size_t)c * 8192;
        const u16* w2g = p.W2t + (size_t)c * 8192;
        u16* w1b = (u16*)(smem + (c & 1) * 16384);
        u16* w2b = (u16*)(smem + 32768 + (c & 1) * 16384);
        #pragma unroll
        for (int f = 0; f < 2; f++) {
            const int fr = wv * 2 + f;
            gl_lds16(w1g + fr * 512 + lane * 8, w1b + fr * 512);
            gl_lds16(w2g + fr * 512 + lane * 8, w2b + fr * 512);
        }
    };

    stage(0);
    __syncthreads();

    for (int c = 0; c < 32; c++) {
        if (c + 1 < 32) stage(c + 1);   // prefetch into alternate buffer

        // ---- gemm1 (swapped): acc1[n2] = D[mid n2*16+..][token], token=l16 ----
        const u16* W1c = (const u16*)(smem + (c & 1) * 16384);
        f32x4 acc1[2];
        acc1[0] = f32x4{0.f, 0.f, 0.f, 0.f};
        acc1[1] = f32x4{0.f, 0.f, 0.f, 0.f};
        #pragma unroll
        for (int kt = 0; kt < 8; kt++) {
            bf16x8 w1f[2];
            #pragma unroll
            for (int n2 = 0; n2 < 2; n2++)
                w1f[n2] = *(const bf16x8*)(W1c + (kt * 2 + n2) * 512 + lane * 8);
            #pragma unroll
            for (int n2 = 0; n2 < 2; n2++)
                acc1[n2] = __builtin_amdgcn_mfma_f32_16x16x32_bf16(w1f[n2], afr[kt], acc1[n2], 0, 0, 0);
        }

        // ---- bias + gelu (exp form) -> packed A-fragment pa ----
        bf16x8 pa;
        #pragma unroll
        for (int n2 = 0; n2 < 2; n2++) {
            const float4 b1q = *(const float4*)(p.b1 + c * 32 + n2 * 16 + quad * 4);
            #pragma unroll
            for (int i = 0; i < 4; i++) {
                const float b1i = (i == 0) ? b1q.x : (i == 1) ? b1q.y : (i == 2) ? b1q.z : b1q.w;
                const float x = acc1[n2][i] + b1i;
                const float u = x * (1.0f + 0.044715f * x * x);
                const float em = __expf(-1.5957691216f * u);
                const float g = x * __builtin_amdgcn_rcpf(1.0f + em);
                pa[n2 * 4 + i] = (__bf16)g;
            }
        }

        // ---- gemm2: acc2[nt] += pa @ W2c (K=32, one MFMA per nt) ----
        const u16* W2c = (const u16*)(smem + 32768 + (c & 1) * 16384);
        #pragma unroll
        for (int nt = 0; nt < 16; nt++) {
            const bf16x8 w2f = *(const bf16x8*)(W2c + nt * 512 + lane * 8);
            acc2[nt] = __builtin_amdgcn_mfma_f32_16x16x32_bf16(pa, w2f, acc2[nt], 0, 0, 0);
        }
        __syncthreads();   // buf[c&1] reads done; stage(c+1) drained (vmcnt0)
    }

    float b2v[16];
    #pragma unroll
    for (int nt = 0; nt < 16; nt++) b2v[nt] = p.b2[nt * 16 + l16];

    // ---- transposed epilogue: 2 chunks of 64 rows through CF (stride 260) ----
    // acc2[nt][i]: token = wtok + quad*4 + i, out = nt*16 + l16.
    #pragma unroll
    for (int cc = 0; cc < 2; cc++) {
        __syncthreads();
        if ((wv >> 2) == cc) {
            const int rb = (wv & 3) * 16;
            #pragma unroll
            for (int nt = 0; nt < 16; nt++)
                #pragma unroll
                for (int i = 0; i < 4; i++)
                    CF[(rb + quad * 4 + i) * 260 + nt * 16 + l16] = acc2[nt][i] + b2v[nt];
        }
        __syncthreads();
        #pragma unroll
        for (int jj = 0; jj < 8; jj++) {
            const int idx = jj * 512 + tid;           // 0..4095
            const int row = idx >> 6, c4 = (idx & 63) << 2;
            const size_t g = (size_t)(tok0 + cc * 64 + row) * 256 + c4;
            const float4 t = *(const float4*)(CF + row * 260 + c4);
            const float4 r = *(const float4*)(p.hin + g);
            float4 o;
            o.x = t.x + r.x; o.y = t.y + r.y; o.z = t.z + r.z; o.w = t.w + r.w;
            *(float4*)(p.hout + g) = o;
        }
    }
}

// ---------------- MFMA attention: one block per (window, head) ----------------
__global__ __launch_bounds__(256, 2) void attn_mfma_kernel(
    const u16* __restrict__ qkv, u16* __restrict__ att,
    const float* __restrict__ rpbp, int D, int shifted, int w0g, int nwsh)
{
    __shared__ __align__(16) char smem[57856];
    u16* Qs = (u16*)smem;
    u16* Ks = (u16*)(smem + 18432);
    u16* Ps = (u16*)smem;
    u16* Vt = (u16*)(smem + 36864);
    float* rb = (float*)(smem + 54272);
    int* lbl = (int*)(smem + 56972);

    const int wloc = blockIdx.x;
    const int head = blockIdx.y;
    const int tid = threadIdx.x;
    const u16* base = qkv + (size_t)wloc * 98304;

    #pragma unroll
    for (int it = 0; it < 4; it++) {
        const int id = it * 256 + tid;
        const int row = id >> 3, oct = id & 7;
        const size_t ro = (size_t)row * 768 + head * 64 + oct * 8;
        *(uint4*)(Qs + row * 72 + oct * 8) = *(const uint4*)(base + ro);
        *(uint4*)(Ks + row * 72 + oct * 8) = *(const uint4*)(base + ro + 256);
        uint4 vv = *(const uint4*)(base + ro + 512);
        const u16* vp = (const u16*)&vv;
        #pragma unroll
        for (int q = 0; q < 8; q++) Vt[(oct * 8 + q) * 136 + row] = vp[q];
    }
    for (int j = tid; j < 675; j += 256) rb[j] = rpbp[j * 4 + head];
    if (tid < 128) {
        int lv = 0;
        if (shifted) {
            const int widx = w0g + wloc;
            const int rem = widx & ((1 << nwsh) - 1);
            const int d0 = rem >> 6, h0 = (rem >> 3) & 7, w0 = rem & 7;
            const int wd = tid >> 6, wh = (tid >> 3) & 7, ww = tid & 7;
            const int rd = (d0 < (D >> 1) - 1) ? 0 : (1 + wd);
            const int rh = (h0 < 7) ? 0 : (1 + (wh >= 4));
            const int rw = (w0 < 7) ? 0 : (1 + (ww >= 4));
            lv = rd * 9 + rh * 3 + rw;
        }
        lbl[tid] = lv;
    }
    __syncthreads();

    const int wq = tid >> 6;
    const int lane = tid & 63;
    const int l16 = lane & 15, quad = lane >> 4;
    const int myrow0 = wq * 32;

    f32x4 sc[2][8];
    #pragma unroll
    for (int mt = 0; mt < 2; mt++)
        #pragma unroll
        for (int nt = 0; nt < 8; nt++)
            sc[mt][nt] = f32x4{0.f, 0.f, 0.f, 0.f};
    #pragma unroll
    for (int kt = 0; kt < 2; kt++) {
        bf16x8 aq[2];
        #pragma unroll
        for (int mt = 0; mt < 2; mt++)
            aq[mt] = *(const bf16x8*)(Qs + (myrow0 + mt * 16 + l16) * 72 + kt * 32 + quad * 8);
        bf16x8 bk[8];
        #pragma unroll
        for (int nt = 0; nt < 8; nt++)
            bk[nt] = *(const bf16x8*)(Ks + (nt * 16 + l16) * 72 + kt * 32 + quad * 8);
        #pragma unroll
        for (int mt = 0; mt < 2; mt++)
            #pragma unroll
            for (int nt = 0; nt < 8; nt++)
                sc[mt][nt] = __builtin_amdgcn_mfma_f32_16x16x32_bf16(aq[mt], bk[nt], sc[mt][nt], 0, 0, 0);
    }

    float linv[2][4];
    #pragma unroll
    for (int mt = 0; mt < 2; mt++) {
        #pragma unroll
        for (int i = 0; i < 4; i++) {
            const int row = myrow0 + mt * 16 + quad * 4 + i;
            const int rbase = ((row >> 6) + 1) * 225 + (((row >> 3) & 7) + 7) * 15 + ((row & 7) + 7);
            const int lq = lbl[row];
            float mx = -1e30f;
            float sv[8];
            #pragma unroll
            for (int nt = 0; nt < 8; nt++) {
                const int col = nt * 16 + l16;
                float v = sc[mt][nt][i] + rb[rbase - (col >> 6) * 225 - ((col >> 3) & 7) * 15 - (col & 7)];
                if (shifted && lq != lbl[col]) v -= 100.0f;
                sv[nt] = v;
                mx = fmaxf(mx, v);
            }
            #pragma unroll
            for (int o = 1; o < 16; o <<= 1) mx = fmaxf(mx, __shfl_xor(mx, o));
            float l = 0.0f;
            #pragma unroll
            for (int nt = 0; nt < 8; nt++) {
                const float pp = __expf(sv[nt] - mx);
                sc[mt][nt][i] = pp;
                l += pp;
            }
            #pragma unroll
            for (int o = 1; o < 16; o <<= 1) l += __shfl_xor(l, o);
            linv[mt][i] = 1.0f / l;
        }
    }

    __syncthreads();
    #pragma unroll
    for (int mt = 0; mt < 2; mt++)
        #pragma unroll
        for (int nt = 0; nt < 8; nt++)
            #pragma unroll
            for (int i = 0; i < 4; i++)
                Ps[(myrow0 + mt * 16 + quad * 4 + i) * 136 + nt * 16 + l16] = f2b(sc[mt][nt][i]);

    f32x4 oc[2][4];
    #pragma unroll
    for (int mt = 0; mt < 2; mt++)
        #pragma unroll
        for (int nt = 0; nt < 4; nt++)
            oc[mt][nt] = f32x4{0.f, 0.f, 0.f, 0.f};
    #pragma unroll
    for (int kt = 0; kt < 4; kt++) {
        bf16x8 ap[2];
        #pragma unroll
        for (int mt = 0; mt < 2; mt++)
            ap[mt] = *(const bf16x8*)(Ps + (myrow0 + mt * 16 + l16) * 136 + kt * 32 + quad * 8);
        bf16x8 bv[4];
        #pragma unroll
        for (int nt = 0; nt < 4; nt++)
            bv[nt] = *(const bf16x8*)(Vt + (nt * 16 + l16) * 136 + kt * 32 + quad * 8);
        #pragma unroll
        for (int mt = 0; mt < 2; mt++)
            #pragma unroll
            for (int nt = 0; nt < 4; nt++)
                oc[mt][nt] = __builtin_amdgcn_mfma_f32_16x16x32_bf16(ap[mt], bv[nt], oc[mt][nt], 0, 0, 0);
    }

    #pragma unroll
    for (int mt = 0; mt < 2; mt++)
        #pragma unroll
        for (int nt = 0; nt < 4; nt++)
            #pragma unroll
            for (int i = 0; i < 4; i++) {
                const int row = myrow0 + mt * 16 + quad * 4 + i;
                const int col = nt * 16 + l16;
                att[(size_t)(wloc * 128 + row) * 256 + head * 64 + col] = f2b(oc[mt][nt][i] * linv[mt][i]);
            }
}

// ---------------- patch-expand LN + reorder ----------------
__global__ __launch_bounds__(256) void expand_ln_kernel(
    const float* __restrict__ sc, float* __restrict__ hout,
    const float* __restrict__ g, const float* __restrict__ bb,
    int it0, int typ)
{
    const int lane = threadIdx.x & 63;
    const int ot = blockIdx.x * 4 + (threadIdx.x >> 6);
    const int itl = ot >> 1, e = ot & 1;
    const float4 xv = *(const float4*)(sc + (size_t)itl * 512 + e * 256 + lane * 4);
    float s = xv.x + xv.y + xv.z + xv.w;
    float s2 = xv.x*xv.x + xv.y*xv.y + xv.z*xv.z + xv.w*xv.w;
    #pragma unroll
    for (int o = 32; o > 0; o >>= 1) { s += __shfl_xor(s, o); s2 += __shfl_xor(s2, o); }
    const float mu = s * 0.00390625f;
    const float var = s2 * 0.00390625f - mu * mu;
    const float rs = 1.0f / sqrtf(var + 1e-5f);
    const int c0 = lane * 4;
    const float4 gv = *(const float4*)(g + c0);
    const float4 bv = *(const float4*)(bb + c0);
    float4 y;
    y.x = (xv.x - mu) * rs * gv.x + bv.x;
    y.y = (xv.y - mu) * rs * gv.y + bv.y;
    y.z = (xv.z - mu) * rs * gv.z + bv.z;
    y.w = (xv.w - mu) * rs * gv.w + bv.w;
    const int it = it0 + itl;
    size_t otg;
    if (typ == 0) {
        const int b = it >> 14, rr = it & 16383;
        const int t = rr >> 13, v = (rr >> 12) & 1, l = rr & 4095;
        otg = (size_t)(((b * 2 + t) * 4 + v * 2 + e) * 4096 + l);
    } else {
        const int b = it >> 15, rr = it & 32767;
        const int t = rr >> 14, v2 = (rr >> 12) & 3, l = rr & 4095;
        otg = (size_t)(((b * 4 + t * 2 + e) * 4 + v2) * 4096 + l);
    }
    *(float4*)(hout + otg * 256 + c0) = y;
}

// ---------------- host ----------------
extern "C" void kernel_launch(void* const* d_in, const int* in_sizes, int n_in,
                              void* d_out, int out_size, void* d_ws, size_t ws_size,
                              hipStream_t stream)
{
    const float* x      = (const float*)d_in[0];
    const float* n1w    = (const float*)d_in[1];
    const float* n1b    = (const float*)d_in[2];
    const float* qkv_w  = (const float*)d_in[3];
    const float* qkv_b  = (const float*)d_in[4];
    const float* rpb    = (const float*)d_in[5];
    const float* proj_w = (const float*)d_in[6];
    const float* proj_b = (const float*)d_in[7];
    const float* n2w    = (const float*)d_in[8];
    const float* n2b    = (const float*)d_in[9];
    const float* mlp1_w = (const float*)d_in[10];
    const float* mlp1_b = (const float*)d_in[11];
    const float* mlp2_w = (const float*)d_in[12];
    const float* mlp2_b = (const float*)d_in[13];
    const float* expv_w = (const float*)d_in[14];
    const float* expv_nw= (const float*)d_in[15];
    const float* expv_nb= (const float*)d_in[16];
    const float* expt_w = (const float*)d_in[17];
    const float* expt_nw= (const float*)d_in[18];
    const float* expt_nb= (const float*)d_in[19];
    (void)in_sizes; (void)n_in; (void)out_size;

    if (ws_size < 352321536ULL) return;

    char* ws = (char*)d_ws;
    float* h    = (float*)ws;
    u16*  winb  = (u16*)(ws + 134217728LL);
    u16*  att   = (u16*)(ws + 134217728LL + 67108864LL);
    char* scr   = ws + 134217728LL + 2LL * 67108864LL;
    u16*  scrb  = (u16*)scr;
    float* scrf = (float*)scr;
    u16* qkvT   = (u16*)(ws + 134217728LL + 3LL * 67108864LL);
    u16* projT  = qkvT + 6 * 768 * 256;
    u16* mlp1T  = projT + 6 * 256 * 256;
    u16* mlp2T  = mlp1T + 6 * 1024 * 256;
    u16* expvT  = mlp2T + 6 * 256 * 1024;
    u16* exptT  = expvT + 512 * 256;

    wt_kernel<<<dim3(768, 6), 256, 0, stream>>>(qkv_w, qkvT, 256, 768);
    wt_kernel<<<dim3(256, 6), 256, 0, stream>>>(proj_w, projT, 256, 256);
    wt1f_kernel<<<dim3(1024, 6), 256, 0, stream>>>(mlp1_w, mlp1T);
    wt2f_kernel<<<dim3(1024, 6), 256, 0, stream>>>(mlp2_w, mlp2T);
    wt_kernel<<<dim3(512, 1), 256, 0, stream>>>(expv_w, expvT, 256, 512);
    wt_kernel<<<dim3(512, 1), 256, 0, stream>>>(expt_w, exptT, 256, 512);
    hipMemcpyAsync(h, x, 33554432ULL, hipMemcpyDeviceToDevice, stream);

    for (int s = 0; s < 3; s++) {
        const int D = 4 << s;
        const int dsh = 2 + s;
        const int nwsh = dsh + 5;
        const int tokens = 2 * D * 4096;
        const int nch = tokens / 32768;
        for (int j = 0; j < 2; j++) {
            const int i = 2 * s + j;
            ln_kernel<<<dim3(tokens / 4), 256, 0, stream>>>(h, winb, n1w + i * 256, n1b + i * 256, D, dsh, j, 0);
            for (int c = 0; c < nch; c++) {
                GemmP gq{};
                gq.A = winb + (size_t)c * 32768 * 256;
                gq.Bt = qkvT + (size_t)i * 768 * 256;
                gq.K = 256; gq.bias = qkv_b + i * 768; gq.outb = scrb;
                gemm_kernel<0><<<dim3(256, 6), 256, 0, stream>>>(gq);
                attn_mfma_kernel<<<dim3(256, 4), 256, 0, stream>>>(scrb, att + (size_t)c * 32768 * 256,
                                                                   rpb + i * 675 * 4, D, j, c * 256, nwsh);
            }
            GemmP gp{};
            gp.A = att; gp.Bt = projT + (size_t)i * 256 * 256; gp.K = 256;
            gp.bias = proj_b + i * 256; gp.hin = h; gp.hout = h;
            gp.D = D; gp.shifted = j; gp.nwsh = nwsh;
            gemm_kernel<1><<<dim3(tokens / 128, 2), 256, 0, stream>>>(gp);
            ln_kernel<<<dim3(tokens / 4), 256, 0, stream>>>(h, winb, n2w + i * 256, n2b + i * 256, D, dsh, 0, 1);
            MlpP mp{};
            mp.A = winb;
            mp.W1t = mlp1T + (size_t)i * 262144;
            mp.W2t = mlp2T + (size_t)i * 262144;
            mp.b1 = mlp1_b + i * 1024;
            mp.b2 = mlp2_b + i * 256;
            mp.hin = h;
            mp.hout = (s == 2 && j == 1) ? (float*)d_out : h;
            mlp_fused_kernel<<<dim3(tokens / 128), 512, 0, stream>>>(mp);
        }
        if (s < 2) {
            const int ntok = tokens;
            cast_kernel<<<dim3(ntok * 64 / 256), 256, 0, stream>>>(h, winb, ntok * 64);
            const u16* eT = (s == 0) ? expvT : exptT;
            const float* eg = (s == 0) ? expv_nw : expt_nw;
            const float* eb = (s == 0) ? expv_nb : expt_nb;
            for (int c = 0; c < ntok / 32768; c++) {
                GemmP ge{};
                ge.A = winb + (size_t)c * 32768 * 256; ge.Bt = eT; ge.K = 256; ge.outf = scrf;
                gemm_kernel<4><<<dim3(256, 4), 256, 0, stream>>>(ge);
                expand_ln_kernel<<<dim3(16384), 256, 0, stream>>>(scrf, h, eg, eb, c * 32768, s);
            }
        }
    }
}